// Round 9
// baseline (1053.889 us; speedup 1.0000x reference)
//
#include <hip/hip_runtime.h>
#include <hip/hip_bf16.h>

#define ALPHA 0.2f
#define L2E 1.4426950408889634f

constexpr int Nn = 4096;
constexpr int FIN = 256;
constexpr int FOUT = 128;
constexpr int JC = 4;    // j-split for k3
constexpr int JQ = 1024; // j per k3 block
constexpr int NCH = 32;  // 32-j chunks per k3 block
constexpr long long SLAB = 2097152;  // 4*4096*128 elems per partial slab

// Diagnostic repetition factors (semantics-preserving; see round notes).
constexpr int REP1 = 32;  // k1b
constexpr int REP2 = 6;   // k2
constexpr int REP3 = 12;  // k3

typedef __attribute__((ext_vector_type(8))) short short8;
typedef __attribute__((ext_vector_type(8))) unsigned short ushort8;
typedef __attribute__((ext_vector_type(4))) float f32x4;
typedef __attribute__((ext_vector_type(16))) float f32x16;
typedef __attribute__((ext_vector_type(4))) int int4v;

__device__ __forceinline__ unsigned short f2bf(float x) {
  unsigned int u = __float_as_uint(x);
  unsigned int r = (u + 0x7fffu + ((u >> 16) & 1u)) >> 16;
  return (unsigned short)r;
}

__device__ __forceinline__ float bf2f(unsigned short v) {
  return __uint_as_float(((unsigned)v) << 16);
}

__device__ __forceinline__ void gload16(const void* g, void* l) {
  auto lp = (__attribute__((address_space(3))) void*)l;
  auto gp = (const __attribute__((address_space(1))) void*)g;
  __builtin_amdgcn_global_load_lds(gp, lp, 16, 0, 0);
}

// ---------------------------------------------------------------------------
// k0: WT bf16 [i=128][k=256] from W f32 [k][i] (LDS transpose). Grid 8.
// ---------------------------------------------------------------------------
__global__ __launch_bounds__(256) void k0_prep(
    const float* __restrict__ W, unsigned short* __restrict__ WT) {
  __shared__ float lw[32][132];
  int t = threadIdx.x;
  int kc0 = blockIdx.x * 32;
#pragma unroll
  for (int m = 0; m < 4; ++m) {
    int idx = t * 16 + m * 4;
    f32x4 v = *(const f32x4*)(W + kc0 * 128 + idx);
    int k = idx >> 7, i0 = idx & 127;
    *(f32x4*)&lw[k][i0] = v;
  }
  __syncthreads();
  int i = t >> 1, half = t & 1;
  unsigned short pk[16];
#pragma unroll
  for (int kk = 0; kk < 16; ++kk) pk[kk] = f2bf(lw[half * 16 + kk][i]);
  ushort8* dst = (ushort8*)(WT + i * 256 + kc0 + half * 16);
  dst[0] = *(ushort8*)&pk[0];
  dst[1] = *(ushort8*)&pk[8];
}

// ---------------------------------------------------------------------------
// k1b: Wh via mfma_16x16x32_bf16. 16-row blocks, grid 1024.
// DIAGNOSTIC: body repeated REP1 times (idempotent rewrites).
// ---------------------------------------------------------------------------
__global__ __launch_bounds__(256) void k1b_wh(
    const float* __restrict__ h, const unsigned short* __restrict__ WT,
    const float* __restrict__ a, unsigned short* __restrict__ whT,
    float* __restrict__ s1L, float* __restrict__ s2L) {
  __shared__ __align__(16) char smem[36864];
  int t = threadIdx.x;
  int w = t >> 6, l = t & 63, g = l >> 4, r = l & 15;
  int r0 = blockIdx.x * 16;
  int b = r0 >> 12, nbase = r0 & 4095;

#pragma unroll 1
  for (int rep = 0; rep < REP1; ++rep) {
    asm volatile("" ::: "memory");
    f32x4 acc[2];
    acc[0] = (f32x4){0.f, 0.f, 0.f, 0.f};
    acc[1] = (f32x4){0.f, 0.f, 0.f, 0.f};

    for (int kc = 0; kc < 2; ++kc) {
      __syncthreads();
      {
        int row = t >> 4, sec = t & 15;
        const f32x4* src = (const f32x4*)(h + (long long)(r0 + row) * 256 +
                                          kc * 128 + sec * 8);
        f32x4 v0 = src[0], v1 = src[1];
        unsigned int pk[4];
        pk[0] = ((unsigned)f2bf(v0.y) << 16) | f2bf(v0.x);
        pk[1] = ((unsigned)f2bf(v0.w) << 16) | f2bf(v0.z);
        pk[2] = ((unsigned)f2bf(v1.y) << 16) | f2bf(v1.x);
        pk[3] = ((unsigned)f2bf(v1.w) << 16) | f2bf(v1.z);
        *(ushort8*)(smem + row * 256 + ((sec ^ (row & 7)) << 4)) =
            *(ushort8*)pk;
      }
      {
        int i = t >> 1, pt = t & 1;
        const ushort8* src =
            (const ushort8*)(WT + i * 256 + kc * 128 + pt * 64);
#pragma unroll
        for (int m = 0; m < 8; ++m) {
          ushort8 v = src[m];
          int slot = pt * 8 + m;
          *(ushort8*)(smem + 4096 + i * 256 + ((slot ^ (i & 7)) << 4)) = v;
        }
      }
      __syncthreads();
#pragma unroll
      for (int kk = 0; kk < 4; ++kk) {
        short8 af =
            *(const short8*)(smem + r * 256 + (((kk * 4 + g) ^ (r & 7)) << 4));
#pragma unroll
        for (int s = 0; s < 2; ++s) {
          int i = w * 32 + s * 16 + r;
          short8 bf = *(const short8*)(smem + 4096 + i * 256 +
                                       (((kk * 4 + g) ^ (i & 7)) << 4));
          acc[s] =
              __builtin_amdgcn_mfma_f32_16x16x32_bf16(af, bf, acc[s], 0, 0, 0);
        }
      }
    }

    __syncthreads();
    unsigned short* tb = (unsigned short*)smem;
#pragma unroll
    for (int s = 0; s < 2; ++s)
#pragma unroll
      for (int q = 0; q < 4; ++q)
        tb[(w * 32 + s * 16 + r) * 25 + g * 4 + q] = f2bf(acc[s][q]);
    __syncthreads();

    {
      int i = t >> 1, half = t & 1;
      ushort8 v = *(const ushort8*)(tb + i * 25 + half * 8);
      *(ushort8*)(whT + (((long long)(b * 128 + i)) << 12) + nbase +
                  half * 8) = v;
    }
    {
      int n = t >> 4, seg = t & 15;
      f32x4 a10 = *(const f32x4*)(a + seg * 8);
      f32x4 a11 = *(const f32x4*)(a + seg * 8 + 4);
      f32x4 a20 = *(const f32x4*)(a + 128 + seg * 8);
      f32x4 a21 = *(const f32x4*)(a + 128 + seg * 8 + 4);
      float v1 = 0.f, v2 = 0.f;
#pragma unroll
      for (int m = 0; m < 8; ++m) {
        float wh = bf2f(tb[(seg * 8 + m) * 25 + n]);
        float c1 = (m < 4) ? a10[m] : a11[m - 4];
        float c2 = (m < 4) ? a20[m] : a21[m - 4];
        v1 += wh * c1;
        v2 += wh * c2;
      }
#pragma unroll
      for (int off = 8; off; off >>= 1) {
        v1 += __shfl_xor(v1, off);
        v2 += __shfl_xor(v2, off);
      }
      if (seg == 0) {
        s1L[r0 + n] = v1 * L2E;
        s2L[r0 + n] = v2 * L2E;
      }
    }
    __syncthreads();
  }
}

// ---------------------------------------------------------------------------
// k2: 2 rows/block, coalesced int4 adj loads, single-pass no-max softmax.
// DIAGNOSTIC: body repeated REP2 times.
// ---------------------------------------------------------------------------
__global__ __launch_bounds__(256) void k2_stats(
    const int* __restrict__ adj, const float* __restrict__ s1L,
    const float* __restrict__ s2L, float2* __restrict__ st2,
    unsigned long long* __restrict__ mask64) {
  __shared__ unsigned int mwords[2][128];
  __shared__ float wsum[2][4];
  int row0 = blockIdx.x * 2;
  int b = row0 >> 12;
  int t = threadIdx.x;
  const int4v* arow0 = (const int4v*)(adj + (long long)row0 * Nn);
  const int4v* arow1 = (const int4v*)(adj + (long long)(row0 + 1) * Nn);
  const f32x4* s2v = (const f32x4*)(s2L + (b << 12));

#pragma unroll 1
  for (int rep = 0; rep < REP2; ++rep) {
    asm volatile("" ::: "memory");
    float s1a = s1L[row0];
    float s1b = s1L[row0 + 1];
    float sumA = 0.f, sumB = 0.f;
#pragma unroll
    for (int q = 0; q < 4; ++q) {
      int4v av0 = arow0[q * 256 + t];
      int4v av1 = arow1[q * 256 + t];
      f32x4 sv = s2v[q * 256 + t];
      unsigned nibA = 0, nibB = 0;
#pragma unroll
      for (int c = 0; c < 4; ++c) {
        float uA = s1a + sv[c];
        float uB = s1b + sv[c];
        float vA = fmaxf(uA, ALPHA * uA);
        float vB = fmaxf(uB, ALPHA * uB);
        sumA = fmaf((float)av0[c], exp2f(vA), sumA);
        sumB = fmaf((float)av1[c], exp2f(vB), sumB);
        nibA |= ((unsigned)av0[c]) << c;
        nibB |= ((unsigned)av1[c]) << c;
      }
      unsigned a1 = nibA | (__shfl_xor(nibA, 1) << 4);
      unsigned a2 = a1 | (__shfl_xor(a1, 2) << 8);
      unsigned a4 = a2 | (__shfl_xor(a2, 4) << 16);
      unsigned b1 = nibB | (__shfl_xor(nibB, 1) << 4);
      unsigned b2 = b1 | (__shfl_xor(b1, 2) << 8);
      unsigned b4 = b2 | (__shfl_xor(b2, 4) << 16);
      if ((t & 7) == 0) {
        mwords[0][q * 32 + (t >> 3)] = a4;
        mwords[1][q * 32 + (t >> 3)] = b4;
      }
    }
#pragma unroll
    for (int off = 32; off; off >>= 1) {
      sumA += __shfl_xor(sumA, off);
      sumB += __shfl_xor(sumB, off);
    }
    if ((t & 63) == 0) {
      wsum[0][t >> 6] = sumA;
      wsum[1][t >> 6] = sumB;
    }
    __syncthreads();
    if (t < 128) {
      int rr = t >> 6, idx = t & 63;
      unsigned long long mv = *(unsigned long long*)&mwords[rr][idx * 2];
      mask64[((long long)(row0 + rr) << 6) + idx] = mv;
    }
    if (t < 2) {
      float S = wsum[t][0] + wsum[t][1] + wsum[t][2] + wsum[t][3];
      float negc = (S > 0.f) ? -log2f(S) : -1.0e30f;
      float s1 = (t == 0) ? s1a : s1b;
      st2[row0 + t] = make_float2(s1 + negc, ALPHA * s1 + negc);
    }
    __syncthreads();
  }
}

// ---------------------------------------------------------------------------
// k3: bf16 partial[jc][b][k][i] = sum_{j in quarter} p[j,k]*Wh[j,i].
// DIAGNOSTIC: body repeated REP3 times.
// ---------------------------------------------------------------------------
__global__ __launch_bounds__(512, 4) void k3_pv(
    const unsigned short* __restrict__ whT, const float2* __restrict__ st2,
    const unsigned long long* __restrict__ mask64,
    const float* __restrict__ s2L, unsigned short* __restrict__ pbuf) {
  __shared__ __align__(16) char smem[40960];
  char* mbase = smem + 16384;
  float2* stl = (float2*)(smem + 32768);

  int t = threadIdx.x;
  int orig = blockIdx.x;
  int x = orig & 7, mm = orig >> 3;
  int b = x >> 1;
  int kt = ((x & 1) << 4) | (mm & 15);
  int jc = mm >> 4;
  int w = t >> 6, l = t & 63, hl = l >> 5, ln = l & 31;
  int ks = w & 3, jh = w >> 2;
  int jq0 = jc * JQ;
  long long brow = (long long)(b << 12);
  int k0 = kt << 7;
  int sh31 = 31 - ln;
  const unsigned short* whTb = whT + ((long long)b << 19);
  int gi = t & 127;
  const unsigned short* wsrc0 =
      whTb + (long long)gi * 4096 + jq0 + (t >> 7) * 8;

#pragma unroll 1
  for (int rep = 0; rep < REP3; ++rep) {
    asm volatile("" ::: "memory");
    __syncthreads();
    float z1 = s2L[brow + k0 + ks * 32 + ln];
    float z2 = ALPHA * z1;

    gload16(st2 + brow + jq0 + t * 2, (char*)stl + t * 16);
    {
      const char* m0 = (const char*)(mask64 + ((brow + jq0 + t) << 6)) + kt * 16;
      const char* m1 =
          (const char*)(mask64 + ((brow + jq0 + 512 + t) << 6)) + kt * 16;
      gload16(m0, mbase + t * 16);
      gload16(m1, mbase + 8192 + t * 16);
    }
    gload16(wsrc0, smem + t * 16);
    __syncthreads();

    f32x16 acc[4];
#pragma unroll
    for (int q = 0; q < 4; ++q)
#pragma unroll
      for (int r = 0; r < 16; ++r) acc[q][r] = 0.f;

    for (int ch = 0; ch < NCH; ++ch) {
      int cur = ch & 1;
      if (ch + 1 < NCH)
        gload16(wsrc0 + (ch + 1) * 32, smem + (cur ^ 1) * 8192 + t * 16);
      char* wb = smem + cur * 8192;
      int jb = ch * 32 + jh * 16 + hl * 8;
      short8 af;
#pragma unroll
      for (int e = 0; e < 8; ++e) {
        int ja = jb + e;
        float2 sc = stl[ja];
        unsigned int mv = *(unsigned int*)(mbase + ja * 16 + ks * 4);
        float e1 = sc.x + z1;
        float e2 = sc.y + z2;
        float p = exp2f(fmaxf(e1, e2));
        int msk = ((int)(mv << sh31)) >> 31;
        unsigned pu = __float_as_uint(p) & (unsigned)msk;
        __hip_bfloat16 hb = __float2bfloat16(__uint_as_float(pu));
        af[e] = *(short*)&hb;
      }
      int gb = (jh * 2 + hl) * 2048;
#pragma unroll
      for (int q = 0; q < 4; ++q) {
        short8 bv = *(const short8*)(wb + gb + ((q * 32 + ln) << 4));
        acc[q] =
            __builtin_amdgcn_mfma_f32_32x32x16_bf16(af, bv, acc[q], 0, 0, 0);
      }
      __syncthreads();
    }

    unsigned short* zone = (unsigned short*)smem;
    if (jh == 1) {
#pragma unroll
      for (int q = 0; q < 4; ++q)
#pragma unroll
        for (int r = 0; r < 16; ++r) {
          int kl = (r & 3) + ((r >> 2) << 3) + (hl << 2);
          zone[ks * 4096 + q * 1024 + kl * 32 + ln] = f2bf(acc[q][r]);
        }
    }
    __syncthreads();
    if (jh == 0) {
      unsigned short* pb = pbuf + (long long)jc * SLAB + ((brow + k0) << 7);
#pragma unroll
      for (int q = 0; q < 4; ++q)
#pragma unroll
        for (int r = 0; r < 16; ++r) {
          int kl = (r & 3) + ((r >> 2) << 3) + (hl << 2);
          float v =
              acc[q][r] + bf2f(zone[ks * 4096 + q * 1024 + kl * 32 + ln]);
          pb[(ks * 32 + kl) * 128 + q * 32 + ln] = f2bf(v);
        }
    }
  }
}

// ---------------------------------------------------------------------------
// k4: out = elu(sum_jc bf16 partial). Grid 1024 x 256, 8 elems/thread.
// ---------------------------------------------------------------------------
__global__ __launch_bounds__(256) void k4_reduce(
    const unsigned short* __restrict__ pbuf, float* __restrict__ out) {
  int orig = blockIdx.x;
  int n = (orig & 7) * 128 + (orig >> 3);
  int base = (n * 256 + threadIdx.x) * 8;
  float s[8] = {0.f, 0.f, 0.f, 0.f, 0.f, 0.f, 0.f, 0.f};
#pragma unroll
  for (int sl = 0; sl < JC; ++sl) {
    ushort8 v = *(const ushort8*)(pbuf + (long long)sl * SLAB + base);
#pragma unroll
    for (int e = 0; e < 8; ++e)
      s[e] += __uint_as_float(((unsigned)(unsigned short)v[e]) << 16);
  }
  f32x4 o0, o1;
#pragma unroll
  for (int e = 0; e < 8; ++e) {
    float xv = s[e];
    float y = xv > 0.f ? xv : expm1f(xv);
    if (e < 4) o0[e] = y; else o1[e - 4] = y;
  }
  *(f32x4*)(out + base) = o0;
  *(f32x4*)(out + base + 4) = o1;
}

extern "C" void kernel_launch(void* const* d_in, const int* in_sizes, int n_in,
                              void* d_out, int out_size, void* d_ws,
                              size_t ws_size, hipStream_t stream) {
  const float* h = (const float*)d_in[0];
  const int* adj = (const int*)d_in[1];
  const float* W = (const float*)d_in[2];
  const float* a = (const float*)d_in[3];
  float* out = (float*)d_out;

  char* ws = (char*)d_ws;
  unsigned short* WT = (unsigned short*)ws;                  // 64 KB
  unsigned short* whT = (unsigned short*)(ws + (1 << 20));   // 4 MB
  float* s1L = (float*)(ws + (5 << 20));                     // 64 KB
  float* s2L = s1L + 16384;                                  // 64 KB
  float2* st2 = (float2*)(ws + (5 << 20) + (128 << 10));     // 128 KB
  unsigned long long* mask64 =
      (unsigned long long*)(ws + (6 << 20));                 // 8 MB
  unsigned short* pbuf = (unsigned short*)(ws + (16 << 20)); // 16 MB bf16

  hipLaunchKernelGGL(k0_prep, dim3(8), dim3(256), 0, stream, W, WT);
  hipLaunchKernelGGL(k1b_wh, dim3(1024), dim3(256), 0, stream, h, WT, a, whT,
                     s1L, s2L);
  hipLaunchKernelGGL(k2_stats, dim3(8192), dim3(256), 0, stream, adj, s1L,
                     s2L, st2, mask64);
  hipLaunchKernelGGL(k3_pv, dim3(512), dim3(512), 0, stream, whT, st2, mask64,
                     s2L, pbuf);
  hipLaunchKernelGGL(k4_reduce, dim3(1024), dim3(256), 0, stream, pbuf, out);
}

// Round 10
// 332.101 us; speedup vs baseline: 3.1734x; 3.1734x over previous
//
#include <hip/hip_runtime.h>
#include <hip/hip_bf16.h>

#define ALPHA 0.2f
#define L2E 1.4426950408889634f

constexpr int Nn = 4096;
constexpr int FIN = 256;
constexpr int FOUT = 128;
constexpr int JC = 8;    // j-split for k3
constexpr int JQ = 512;  // j per k3 block
constexpr int NCH = 16;  // 32-j chunks per k3 block
constexpr long long SLAB = 2097152;  // 4*4096*128 elems per partial slab

typedef __attribute__((ext_vector_type(8))) short short8;
typedef __attribute__((ext_vector_type(8))) unsigned short ushort8;
typedef __attribute__((ext_vector_type(4))) float f32x4;
typedef __attribute__((ext_vector_type(16))) float f32x16;
typedef __attribute__((ext_vector_type(4))) int int4v;
typedef __attribute__((ext_vector_type(4))) unsigned int uint4v;

__device__ __forceinline__ unsigned short f2bf(float x) {
  unsigned int u = __float_as_uint(x);
  unsigned int r = (u + 0x7fffu + ((u >> 16) & 1u)) >> 16;
  return (unsigned short)r;
}

__device__ __forceinline__ float bf2f(unsigned short v) {
  return __uint_as_float(((unsigned)v) << 16);
}

__device__ __forceinline__ void gload16(const void* g, void* l) {
  auto lp = (__attribute__((address_space(3))) void*)l;
  auto gp = (const __attribute__((address_space(1))) void*)g;
  __builtin_amdgcn_global_load_lds(gp, lp, 16, 0, 0);
}

// ---------------------------------------------------------------------------
// k0: WT bf16 [i=128][k=256] from W f32 [k][i] (LDS transpose). Grid 8.
// Block 0 also zeroes the k3 fan-in counters (graph-replay safe).
// ---------------------------------------------------------------------------
__global__ __launch_bounds__(256) void k0_prep(
    const float* __restrict__ W, unsigned short* __restrict__ WT,
    int* __restrict__ cnt) {
  __shared__ float lw[32][132];
  int t = threadIdx.x;
  if (blockIdx.x == 0 && t < 128) cnt[t] = 0;
  int kc0 = blockIdx.x * 32;
#pragma unroll
  for (int m = 0; m < 4; ++m) {
    int idx = t * 16 + m * 4;
    f32x4 v = *(const f32x4*)(W + kc0 * 128 + idx);
    int k = idx >> 7, i0 = idx & 127;
    *(f32x4*)&lw[k][i0] = v;
  }
  __syncthreads();
  int i = t >> 1, half = t & 1;
  unsigned short pk[16];
#pragma unroll
  for (int kk = 0; kk < 16; ++kk) pk[kk] = f2bf(lw[half * 16 + kk][i]);
  ushort8* dst = (ushort8*)(WT + i * 256 + kc0 + half * 16);
  dst[0] = *(ushort8*)&pk[0];
  dst[1] = *(ushort8*)&pk[8];
}

// ---------------------------------------------------------------------------
// k1b: Wh via mfma_16x16x32_bf16. 16-row blocks, grid 1024.
// Emits whT bf16 [b][i=128][n=4096] AND s1L/s2L (x log2 e).
// ---------------------------------------------------------------------------
__global__ __launch_bounds__(256) void k1b_wh(
    const float* __restrict__ h, const unsigned short* __restrict__ WT,
    const float* __restrict__ a, unsigned short* __restrict__ whT,
    float* __restrict__ s1L, float* __restrict__ s2L) {
  __shared__ __align__(16) char smem[36864];
  int t = threadIdx.x;
  int w = t >> 6, l = t & 63, g = l >> 4, r = l & 15;
  int r0 = blockIdx.x * 16;
  int b = r0 >> 12, nbase = r0 & 4095;

  f32x4 acc[2];
  acc[0] = (f32x4){0.f, 0.f, 0.f, 0.f};
  acc[1] = (f32x4){0.f, 0.f, 0.f, 0.f};

  for (int kc = 0; kc < 2; ++kc) {
    __syncthreads();
    {
      int row = t >> 4, sec = t & 15;
      const f32x4* src =
          (const f32x4*)(h + (long long)(r0 + row) * 256 + kc * 128 + sec * 8);
      f32x4 v0 = src[0], v1 = src[1];
      unsigned int pk[4];
      pk[0] = ((unsigned)f2bf(v0.y) << 16) | f2bf(v0.x);
      pk[1] = ((unsigned)f2bf(v0.w) << 16) | f2bf(v0.z);
      pk[2] = ((unsigned)f2bf(v1.y) << 16) | f2bf(v1.x);
      pk[3] = ((unsigned)f2bf(v1.w) << 16) | f2bf(v1.z);
      *(ushort8*)(smem + row * 256 + ((sec ^ (row & 7)) << 4)) = *(ushort8*)pk;
    }
    {
      int i = t >> 1, pt = t & 1;
      const ushort8* src = (const ushort8*)(WT + i * 256 + kc * 128 + pt * 64);
#pragma unroll
      for (int m = 0; m < 8; ++m) {
        ushort8 v = src[m];
        int slot = pt * 8 + m;
        *(ushort8*)(smem + 4096 + i * 256 + ((slot ^ (i & 7)) << 4)) = v;
      }
    }
    __syncthreads();
#pragma unroll
    for (int kk = 0; kk < 4; ++kk) {
      short8 af =
          *(const short8*)(smem + r * 256 + (((kk * 4 + g) ^ (r & 7)) << 4));
#pragma unroll
      for (int s = 0; s < 2; ++s) {
        int i = w * 32 + s * 16 + r;
        short8 bf = *(const short8*)(smem + 4096 + i * 256 +
                                     (((kk * 4 + g) ^ (i & 7)) << 4));
        acc[s] =
            __builtin_amdgcn_mfma_f32_16x16x32_bf16(af, bf, acc[s], 0, 0, 0);
      }
    }
  }

  __syncthreads();
  unsigned short* tb = (unsigned short*)smem;  // [128][25]
#pragma unroll
  for (int s = 0; s < 2; ++s)
#pragma unroll
    for (int q = 0; q < 4; ++q)
      tb[(w * 32 + s * 16 + r) * 25 + g * 4 + q] = f2bf(acc[s][q]);
  __syncthreads();

  {
    int i = t >> 1, half = t & 1;
    ushort8 v = *(const ushort8*)(tb + i * 25 + half * 8);
    *(ushort8*)(whT + (((long long)(b * 128 + i)) << 12) + nbase + half * 8) =
        v;
  }
  {
    int n = t >> 4, seg = t & 15;
    f32x4 a10 = *(const f32x4*)(a + seg * 8);
    f32x4 a11 = *(const f32x4*)(a + seg * 8 + 4);
    f32x4 a20 = *(const f32x4*)(a + 128 + seg * 8);
    f32x4 a21 = *(const f32x4*)(a + 128 + seg * 8 + 4);
    float v1 = 0.f, v2 = 0.f;
#pragma unroll
    for (int m = 0; m < 8; ++m) {
      float wh = bf2f(tb[(seg * 8 + m) * 25 + n]);
      float c1 = (m < 4) ? a10[m] : a11[m - 4];
      float c2 = (m < 4) ? a20[m] : a21[m - 4];
      v1 += wh * c1;
      v2 += wh * c2;
    }
#pragma unroll
    for (int off = 8; off; off >>= 1) {
      v1 += __shfl_xor(v1, off);
      v2 += __shfl_xor(v2, off);
    }
    if (seg == 0) {
      s1L[r0 + n] = v1 * L2E;
      s2L[r0 + n] = v2 * L2E;
    }
  }
}

// ---------------------------------------------------------------------------
// k2: 2 rows/block, coalesced int4 adj loads, single-pass no-max softmax in
// exp2 domain; mask via shfl_xor nibble merge. st2[row] = {s1L + negc,
// ALPHA*s1L + negc}. Grid 8192 x 256. ~45us, at the 268MB adj HBM wall.
// ---------------------------------------------------------------------------
__global__ __launch_bounds__(256) void k2_stats(
    const int* __restrict__ adj, const float* __restrict__ s1L,
    const float* __restrict__ s2L, float2* __restrict__ st2,
    unsigned long long* __restrict__ mask64) {
  __shared__ unsigned int mwords[2][128];
  __shared__ float wsum[2][4];
  int row0 = blockIdx.x * 2;
  int b = row0 >> 12;
  int t = threadIdx.x;
  float s1a = s1L[row0];
  float s1b = s1L[row0 + 1];
  const int4v* arow0 = (const int4v*)(adj + (long long)row0 * Nn);
  const int4v* arow1 = (const int4v*)(adj + (long long)(row0 + 1) * Nn);
  const f32x4* s2v = (const f32x4*)(s2L + (b << 12));

  float sumA = 0.f, sumB = 0.f;
#pragma unroll
  for (int q = 0; q < 4; ++q) {
    int4v av0 = arow0[q * 256 + t];
    int4v av1 = arow1[q * 256 + t];
    f32x4 sv = s2v[q * 256 + t];
    unsigned nibA = 0, nibB = 0;
#pragma unroll
    for (int c = 0; c < 4; ++c) {
      float uA = s1a + sv[c];
      float uB = s1b + sv[c];
      float vA = fmaxf(uA, ALPHA * uA);
      float vB = fmaxf(uB, ALPHA * uB);
      sumA = fmaf((float)av0[c], exp2f(vA), sumA);
      sumB = fmaf((float)av1[c], exp2f(vB), sumB);
      nibA |= ((unsigned)av0[c]) << c;
      nibB |= ((unsigned)av1[c]) << c;
    }
    unsigned a1 = nibA | (__shfl_xor(nibA, 1) << 4);
    unsigned a2 = a1 | (__shfl_xor(a1, 2) << 8);
    unsigned a4 = a2 | (__shfl_xor(a2, 4) << 16);
    unsigned b1 = nibB | (__shfl_xor(nibB, 1) << 4);
    unsigned b2 = b1 | (__shfl_xor(b1, 2) << 8);
    unsigned b4 = b2 | (__shfl_xor(b2, 4) << 16);
    if ((t & 7) == 0) {
      mwords[0][q * 32 + (t >> 3)] = a4;
      mwords[1][q * 32 + (t >> 3)] = b4;
    }
  }
#pragma unroll
  for (int off = 32; off; off >>= 1) {
    sumA += __shfl_xor(sumA, off);
    sumB += __shfl_xor(sumB, off);
  }
  if ((t & 63) == 0) {
    wsum[0][t >> 6] = sumA;
    wsum[1][t >> 6] = sumB;
  }
  __syncthreads();
  if (t < 128) {
    int rr = t >> 6, idx = t & 63;
    unsigned long long mv = *(unsigned long long*)&mwords[rr][idx * 2];
    mask64[((long long)(row0 + rr) << 6) + idx] = mv;
  }
  if (t < 2) {
    float S = wsum[t][0] + wsum[t][1] + wsum[t][2] + wsum[t][3];
    float negc = (S > 0.f) ? -log2f(S) : -1.0e30f;
    float s1 = (t == 0) ? s1a : s1b;
    st2[row0 + t] = make_float2(s1 + negc, ALPHA * s1 + negc);
  }
}

// ---------------------------------------------------------------------------
// k3: bf16 partial[jc][b][k][i] = sum_{j in eighth} p[j,k]*Wh[j,i], then
// fan-in: last block of each (b,kt) group reduces 8 slabs + ELU + store.
// Grid 1024 = 4b x 8jc x 32kt; XCD map: x=orig&7 -> (b, kt-half); all 8 jc
// of a (b,kt) share one XCD (L2-local slabs). 512 thr = 4 ks x 2 jh.
// LDS 40KB: whT dbuf 2x8K @0 (granule joct*128+i), mask planes mk[4][512]
// @16K (8K), stl float2[512] @24K (4K); merge zone 32K aliases @0.
// ---------------------------------------------------------------------------
__global__ __launch_bounds__(512, 4) void k3_pv(
    const unsigned short* __restrict__ whT, const float2* __restrict__ st2,
    const unsigned long long* __restrict__ mask64,
    const float* __restrict__ s2L, unsigned short* __restrict__ pbuf,
    int* __restrict__ cnt, float* __restrict__ out) {
  __shared__ __align__(16) char smem[40960];
  unsigned int* mkpl = (unsigned int*)(smem + 16384);  // [4][512]
  float2* stl = (float2*)(smem + 24576);               // [512]

  int t = threadIdx.x;
  int orig = blockIdx.x;
  int x = orig & 7, mm = orig >> 3;
  int b = x >> 1;
  int kt = ((x & 1) << 4) | (mm & 15);
  int jc = mm >> 4;
  int w = t >> 6, l = t & 63, hl = l >> 5, ln = l & 31;
  int ks = w & 3, jh = w >> 2;
  int jq0 = jc * JQ;
  long long brow = (long long)(b << 12);
  int k0 = kt << 7;
  float z1 = s2L[brow + k0 + ks * 32 + ln];
  float z2 = ALPHA * z1;
  int sh31 = 31 - ln;

  // stage-once: stl (4KB, gload16), mask planes (reg-staged scatter)
  if (t < 256) gload16(st2 + brow + jq0 + t * 2, (char*)stl + t * 16);
  {
    uint4v mrow = *(const uint4v*)((const char*)(mask64 +
                                                 ((brow + jq0 + t) << 6)) +
                                   kt * 16);
    mkpl[0 * 512 + t] = mrow[0];
    mkpl[1 * 512 + t] = mrow[1];
    mkpl[2 * 512 + t] = mrow[2];
    mkpl[3 * 512 + t] = mrow[3];
  }
  // whT chunk 0: thread t -> granule (joct=t>>7, gi=t&127), linear LDS dest
  const unsigned short* whTb = whT + ((long long)b << 19);
  int gi = t & 127;
  const unsigned short* wsrc0 = whTb + (long long)gi * 4096 + jq0 + (t >> 7) * 8;
  gload16(wsrc0, smem + t * 16);
  __syncthreads();

  f32x16 acc[4];
#pragma unroll
  for (int q = 0; q < 4; ++q)
#pragma unroll
    for (int r = 0; r < 16; ++r) acc[q][r] = 0.f;

  const unsigned int* mkw = mkpl + ks * 512;
  for (int ch = 0; ch < NCH; ++ch) {
    int cur = ch & 1;
    if (ch + 1 < NCH)
      gload16(wsrc0 + (ch + 1) * 32, smem + (cur ^ 1) * 8192 + t * 16);
    char* wb = smem + cur * 8192;
    int jb = ch * 32 + jh * 16 + hl * 8;
    // 8 mask words + 8 st2 pairs: wave-uniform vector LDS reads
    uint4v mw0 = *(const uint4v*)(mkw + jb);
    uint4v mw1 = *(const uint4v*)(mkw + jb + 4);
    short8 af;
#pragma unroll
    for (int e = 0; e < 8; ++e) {
      float2 sc = stl[jb + e];
      unsigned mv = (e < 4) ? mw0[e] : mw1[e - 4];
      float e1 = sc.x + z1;
      float e2 = sc.y + z2;
      float p = exp2f(fmaxf(e1, e2));
      int msk = ((int)(mv << sh31)) >> 31;
      unsigned pu = __float_as_uint(p) & (unsigned)msk;
      __hip_bfloat16 hb = __float2bfloat16(__uint_as_float(pu));
      af[e] = *(short*)&hb;
    }
    int gb = (jh * 2 + hl) * 2048;
#pragma unroll
    for (int q = 0; q < 4; ++q) {
      short8 bv = *(const short8*)(wb + gb + ((q * 32 + ln) << 4));
      acc[q] = __builtin_amdgcn_mfma_f32_32x32x16_bf16(af, bv, acc[q], 0, 0, 0);
    }
    __syncthreads();
  }

  // jh-merge via bf16 zone (aliases smem), then slab store
  unsigned short* zone = (unsigned short*)smem;
  if (jh == 1) {
#pragma unroll
    for (int q = 0; q < 4; ++q)
#pragma unroll
      for (int r = 0; r < 16; ++r) {
        int kl = (r & 3) + ((r >> 2) << 3) + (hl << 2);
        zone[ks * 4096 + q * 1024 + kl * 32 + ln] = f2bf(acc[q][r]);
      }
  }
  __syncthreads();
  long long rbase = (brow + k0) << 7;
  if (jh == 0) {
    unsigned short* pb = pbuf + (long long)jc * SLAB + rbase;
#pragma unroll
    for (int q = 0; q < 4; ++q)
#pragma unroll
      for (int r = 0; r < 16; ++r) {
        int kl = (r & 3) + ((r >> 2) << 3) + (hl << 2);
        float v = acc[q][r] + bf2f(zone[ks * 4096 + q * 1024 + kl * 32 + ln]);
        pb[(ks * 32 + kl) * 128 + q * 32 + ln] = f2bf(v);
      }
  }

  // fan-in: last of the 8 jc-blocks for (b,kt) reduces + ELU + stores out
  __threadfence();
  __syncthreads();
  int* flag = (int*)(smem + 40000);
  if (t == 0) *flag = (atomicAdd(&cnt[b * 32 + kt], 1) == JC - 1) ? 1 : 0;
  __syncthreads();
  if (*flag) {
    __threadfence();  // acquire: other blocks' slab stores
#pragma unroll
    for (int m = 0; m < 4; ++m) {
      int idx = m * 4096 + t * 8;
      float s[8] = {0.f, 0.f, 0.f, 0.f, 0.f, 0.f, 0.f, 0.f};
#pragma unroll
      for (int sl = 0; sl < JC; ++sl) {
        ushort8 v = *(const ushort8*)(pbuf + (long long)sl * SLAB + rbase + idx);
#pragma unroll
        for (int e = 0; e < 8; ++e) s[e] += bf2f((unsigned short)v[e]);
      }
      f32x4 o0, o1;
#pragma unroll
      for (int e = 0; e < 8; ++e) {
        float xv = s[e];
        float y = xv > 0.f ? xv : expm1f(xv);
        if (e < 4) o0[e] = y; else o1[e - 4] = y;
      }
      *(f32x4*)(out + rbase + idx) = o0;
      *(f32x4*)(out + rbase + idx + 4) = o1;
    }
  }
}

extern "C" void kernel_launch(void* const* d_in, const int* in_sizes, int n_in,
                              void* d_out, int out_size, void* d_ws,
                              size_t ws_size, hipStream_t stream) {
  const float* h = (const float*)d_in[0];
  const int* adj = (const int*)d_in[1];
  const float* W = (const float*)d_in[2];
  const float* a = (const float*)d_in[3];
  float* out = (float*)d_out;

  char* ws = (char*)d_ws;
  unsigned short* WT = (unsigned short*)ws;                  // 64 KB
  unsigned short* whT = (unsigned short*)(ws + (1 << 20));   // 4 MB
  float* s1L = (float*)(ws + (5 << 20));                     // 64 KB
  float* s2L = s1L + 16384;                                  // 64 KB
  float2* st2 = (float2*)(ws + (5 << 20) + (128 << 10));     // 128 KB
  int* cnt = (int*)(ws + (5 << 20) + (512 << 10));           // 512 B
  unsigned long long* mask64 =
      (unsigned long long*)(ws + (6 << 20));                 // 8 MB
  unsigned short* pbuf = (unsigned short*)(ws + (16 << 20)); // 32 MB bf16

  hipLaunchKernelGGL(k0_prep, dim3(8), dim3(256), 0, stream, W, WT, cnt);
  hipLaunchKernelGGL(k1b_wh, dim3(1024), dim3(256), 0, stream, h, WT, a, whT,
                     s1L, s2L);
  hipLaunchKernelGGL(k2_stats, dim3(8192), dim3(256), 0, stream, adj, s1L,
                     s2L, st2, mask64);
  hipLaunchKernelGGL(k3_pv, dim3(1024), dim3(512), 0, stream, whT, st2,
                     mask64, s2L, pbuf, cnt, out);
}

// Round 11
// 129.918 us; speedup vs baseline: 8.1120x; 2.5562x over previous
//
#include <hip/hip_runtime.h>
#include <hip/hip_bf16.h>

#define ALPHA 0.2f
#define L2E 1.4426950408889634f

constexpr int Nn = 4096;
constexpr int FIN = 256;
constexpr int FOUT = 128;
constexpr int JC = 8;    // j-split for k3
constexpr int JQ = 512;  // j per k3 block
constexpr int NCH = 16;  // 32-j chunks per k3 block
constexpr long long SLAB = 2097152;  // 4*4096*128 elems per partial slab

typedef __attribute__((ext_vector_type(8))) short short8;
typedef __attribute__((ext_vector_type(8))) unsigned short ushort8;
typedef __attribute__((ext_vector_type(4))) float f32x4;
typedef __attribute__((ext_vector_type(16))) float f32x16;
typedef __attribute__((ext_vector_type(4))) int int4v;
typedef __attribute__((ext_vector_type(4))) unsigned int uint4v;

__device__ __forceinline__ unsigned short f2bf(float x) {
  unsigned int u = __float_as_uint(x);
  unsigned int r = (u + 0x7fffu + ((u >> 16) & 1u)) >> 16;
  return (unsigned short)r;
}

__device__ __forceinline__ float bf2f(unsigned short v) {
  return __uint_as_float(((unsigned)v) << 16);
}

__device__ __forceinline__ void gload16(const void* g, void* l) {
  auto lp = (__attribute__((address_space(3))) void*)l;
  auto gp = (const __attribute__((address_space(1))) void*)g;
  __builtin_amdgcn_global_load_lds(gp, lp, 16, 0, 0);
}

// ---------------------------------------------------------------------------
// k0: WT bf16 [i=128][k=256] from W f32 [k][i] (LDS transpose). Grid 8.
// ---------------------------------------------------------------------------
__global__ __launch_bounds__(256) void k0_prep(
    const float* __restrict__ W, unsigned short* __restrict__ WT) {
  __shared__ float lw[32][132];
  int t = threadIdx.x;
  int kc0 = blockIdx.x * 32;
#pragma unroll
  for (int m = 0; m < 4; ++m) {
    int idx = t * 16 + m * 4;
    f32x4 v = *(const f32x4*)(W + kc0 * 128 + idx);
    int k = idx >> 7, i0 = idx & 127;
    *(f32x4*)&lw[k][i0] = v;
  }
  __syncthreads();
  int i = t >> 1, half = t & 1;
  unsigned short pk[16];
#pragma unroll
  for (int kk = 0; kk < 16; ++kk) pk[kk] = f2bf(lw[half * 16 + kk][i]);
  ushort8* dst = (ushort8*)(WT + i * 256 + kc0 + half * 16);
  dst[0] = *(ushort8*)&pk[0];
  dst[1] = *(ushort8*)&pk[8];
}

// ---------------------------------------------------------------------------
// k1b: Wh via mfma_16x16x32_bf16. 16-row blocks, grid 1024.
// Emits whT bf16 [b][i=128][n=4096] AND s1L/s2L (x log2 e).
// ---------------------------------------------------------------------------
__global__ __launch_bounds__(256) void k1b_wh(
    const float* __restrict__ h, const unsigned short* __restrict__ WT,
    const float* __restrict__ a, unsigned short* __restrict__ whT,
    float* __restrict__ s1L, float* __restrict__ s2L) {
  __shared__ __align__(16) char smem[36864];
  int t = threadIdx.x;
  int w = t >> 6, l = t & 63, g = l >> 4, r = l & 15;
  int r0 = blockIdx.x * 16;
  int b = r0 >> 12, nbase = r0 & 4095;

  f32x4 acc[2];
  acc[0] = (f32x4){0.f, 0.f, 0.f, 0.f};
  acc[1] = (f32x4){0.f, 0.f, 0.f, 0.f};

  for (int kc = 0; kc < 2; ++kc) {
    __syncthreads();
    {
      int row = t >> 4, sec = t & 15;
      const f32x4* src =
          (const f32x4*)(h + (long long)(r0 + row) * 256 + kc * 128 + sec * 8);
      f32x4 v0 = src[0], v1 = src[1];
      unsigned int pk[4];
      pk[0] = ((unsigned)f2bf(v0.y) << 16) | f2bf(v0.x);
      pk[1] = ((unsigned)f2bf(v0.w) << 16) | f2bf(v0.z);
      pk[2] = ((unsigned)f2bf(v1.y) << 16) | f2bf(v1.x);
      pk[3] = ((unsigned)f2bf(v1.w) << 16) | f2bf(v1.z);
      *(ushort8*)(smem + row * 256 + ((sec ^ (row & 7)) << 4)) = *(ushort8*)pk;
    }
    {
      int i = t >> 1, pt = t & 1;
      const ushort8* src = (const ushort8*)(WT + i * 256 + kc * 128 + pt * 64);
#pragma unroll
      for (int m = 0; m < 8; ++m) {
        ushort8 v = src[m];
        int slot = pt * 8 + m;
        *(ushort8*)(smem + 4096 + i * 256 + ((slot ^ (i & 7)) << 4)) = v;
      }
    }
    __syncthreads();
#pragma unroll
    for (int kk = 0; kk < 4; ++kk) {
      short8 af =
          *(const short8*)(smem + r * 256 + (((kk * 4 + g) ^ (r & 7)) << 4));
#pragma unroll
      for (int s = 0; s < 2; ++s) {
        int i = w * 32 + s * 16 + r;
        short8 bf = *(const short8*)(smem + 4096 + i * 256 +
                                     (((kk * 4 + g) ^ (i & 7)) << 4));
        acc[s] =
            __builtin_amdgcn_mfma_f32_16x16x32_bf16(af, bf, acc[s], 0, 0, 0);
      }
    }
  }

  __syncthreads();
  unsigned short* tb = (unsigned short*)smem;  // [128][25]
#pragma unroll
  for (int s = 0; s < 2; ++s)
#pragma unroll
    for (int q = 0; q < 4; ++q)
      tb[(w * 32 + s * 16 + r) * 25 + g * 4 + q] = f2bf(acc[s][q]);
  __syncthreads();

  {
    int i = t >> 1, half = t & 1;
    ushort8 v = *(const ushort8*)(tb + i * 25 + half * 8);
    *(ushort8*)(whT + (((long long)(b * 128 + i)) << 12) + nbase + half * 8) =
        v;
  }
  {
    int n = t >> 4, seg = t & 15;
    f32x4 a10 = *(const f32x4*)(a + seg * 8);
    f32x4 a11 = *(const f32x4*)(a + seg * 8 + 4);
    f32x4 a20 = *(const f32x4*)(a + 128 + seg * 8);
    f32x4 a21 = *(const f32x4*)(a + 128 + seg * 8 + 4);
    float v1 = 0.f, v2 = 0.f;
#pragma unroll
    for (int m = 0; m < 8; ++m) {
      float wh = bf2f(tb[(seg * 8 + m) * 25 + n]);
      float c1 = (m < 4) ? a10[m] : a11[m - 4];
      float c2 = (m < 4) ? a20[m] : a21[m - 4];
      v1 += wh * c1;
      v2 += wh * c2;
    }
#pragma unroll
    for (int off = 8; off; off >>= 1) {
      v1 += __shfl_xor(v1, off);
      v2 += __shfl_xor(v2, off);
    }
    if (seg == 0) {
      s1L[r0 + n] = v1 * L2E;
      s2L[r0 + n] = v2 * L2E;
    }
  }
}

// ---------------------------------------------------------------------------
// k2: 2 rows/block, coalesced int4 adj loads, single-pass no-max softmax in
// exp2 domain; mask via shfl_xor nibble merge. st2[row] = {s1L + negc,
// ALPHA*s1L + negc}. Grid 8192 x 256. ~45us, at the 268MB adj HBM wall.
// ---------------------------------------------------------------------------
__global__ __launch_bounds__(256) void k2_stats(
    const int* __restrict__ adj, const float* __restrict__ s1L,
    const float* __restrict__ s2L, float2* __restrict__ st2,
    unsigned long long* __restrict__ mask64) {
  __shared__ unsigned int mwords[2][128];
  __shared__ float wsum[2][4];
  int row0 = blockIdx.x * 2;
  int b = row0 >> 12;
  int t = threadIdx.x;
  float s1a = s1L[row0];
  float s1b = s1L[row0 + 1];
  const int4v* arow0 = (const int4v*)(adj + (long long)row0 * Nn);
  const int4v* arow1 = (const int4v*)(adj + (long long)(row0 + 1) * Nn);
  const f32x4* s2v = (const f32x4*)(s2L + (b << 12));

  float sumA = 0.f, sumB = 0.f;
#pragma unroll
  for (int q = 0; q < 4; ++q) {
    int4v av0 = arow0[q * 256 + t];
    int4v av1 = arow1[q * 256 + t];
    f32x4 sv = s2v[q * 256 + t];
    unsigned nibA = 0, nibB = 0;
#pragma unroll
    for (int c = 0; c < 4; ++c) {
      float uA = s1a + sv[c];
      float uB = s1b + sv[c];
      float vA = fmaxf(uA, ALPHA * uA);
      float vB = fmaxf(uB, ALPHA * uB);
      sumA = fmaf((float)av0[c], exp2f(vA), sumA);
      sumB = fmaf((float)av1[c], exp2f(vB), sumB);
      nibA |= ((unsigned)av0[c]) << c;
      nibB |= ((unsigned)av1[c]) << c;
    }
    unsigned a1 = nibA | (__shfl_xor(nibA, 1) << 4);
    unsigned a2 = a1 | (__shfl_xor(a1, 2) << 8);
    unsigned a4 = a2 | (__shfl_xor(a2, 4) << 16);
    unsigned b1 = nibB | (__shfl_xor(nibB, 1) << 4);
    unsigned b2 = b1 | (__shfl_xor(b1, 2) << 8);
    unsigned b4 = b2 | (__shfl_xor(b2, 4) << 16);
    if ((t & 7) == 0) {
      mwords[0][q * 32 + (t >> 3)] = a4;
      mwords[1][q * 32 + (t >> 3)] = b4;
    }
  }
#pragma unroll
  for (int off = 32; off; off >>= 1) {
    sumA += __shfl_xor(sumA, off);
    sumB += __shfl_xor(sumB, off);
  }
  if ((t & 63) == 0) {
    wsum[0][t >> 6] = sumA;
    wsum[1][t >> 6] = sumB;
  }
  __syncthreads();
  if (t < 128) {
    int rr = t >> 6, idx = t & 63;
    unsigned long long mv = *(unsigned long long*)&mwords[rr][idx * 2];
    mask64[((long long)(row0 + rr) << 6) + idx] = mv;
  }
  if (t < 2) {
    float S = wsum[t][0] + wsum[t][1] + wsum[t][2] + wsum[t][3];
    float negc = (S > 0.f) ? -log2f(S) : -1.0e30f;
    float s1 = (t == 0) ? s1a : s1b;
    st2[row0 + t] = make_float2(s1 + negc, ALPHA * s1 + negc);
  }
}

// ---------------------------------------------------------------------------
// k3: bf16 partial[jc][b][k][i] = sum_{j in eighth} p[j,k]*Wh[j,i].
// Grid 1024 = 4b x 8jc x 32kt (4 blocks/CU); tile m=b*32+kt lives on XCD
// m>>4 (all 8 jc-blocks of a tile share XCD). 512 thr = 4 ks x 2 jh.
// LDS 40KB: whT dbuf 2x8K @0 (granule joct*128+i), mask planes mk[4][512]
// @16K (8K), stl float2[512] @24K (4K); merge zone 32K aliases @0.
// NO fences/atomics (R10 lesson: per-block device-scope fence = L2 writeback
// storm, 5x regression).
// ---------------------------------------------------------------------------
__global__ __launch_bounds__(512, 4) void k3_pv(
    const unsigned short* __restrict__ whT, const float2* __restrict__ st2,
    const unsigned long long* __restrict__ mask64,
    const float* __restrict__ s2L, unsigned short* __restrict__ pbuf) {
  __shared__ __align__(16) char smem[40960];
  unsigned int* mkpl = (unsigned int*)(smem + 16384);  // [4][512]
  float2* stl = (float2*)(smem + 24576);               // [512]

  int t = threadIdx.x;
  int orig = blockIdx.x;
  int x = orig & 7, mm = orig >> 3;
  int b = x >> 1;
  int kt = ((x & 1) << 4) | (mm & 15);
  int jc = mm >> 4;
  int w = t >> 6, l = t & 63, hl = l >> 5, ln = l & 31;
  int ks = w & 3, jh = w >> 2;
  int jq0 = jc * JQ;
  long long brow = (long long)(b << 12);
  int k0 = kt << 7;
  float z1 = s2L[brow + k0 + ks * 32 + ln];
  float z2 = ALPHA * z1;
  int sh31 = 31 - ln;

  // stage-once: stl (4KB, gload16), mask planes (reg-staged scatter)
  if (t < 256) gload16(st2 + brow + jq0 + t * 2, (char*)stl + t * 16);
  {
    uint4v mrow = *(const uint4v*)((const char*)(mask64 +
                                                 ((brow + jq0 + t) << 6)) +
                                   kt * 16);
    mkpl[0 * 512 + t] = mrow[0];
    mkpl[1 * 512 + t] = mrow[1];
    mkpl[2 * 512 + t] = mrow[2];
    mkpl[3 * 512 + t] = mrow[3];
  }
  // whT chunk 0: thread t -> granule (joct=t>>7, gi=t&127), linear LDS dest
  const unsigned short* whTb = whT + ((long long)b << 19);
  int gi = t & 127;
  const unsigned short* wsrc0 = whTb + (long long)gi * 4096 + jq0 + (t >> 7) * 8;
  gload16(wsrc0, smem + t * 16);
  __syncthreads();

  f32x16 acc[4];
#pragma unroll
  for (int q = 0; q < 4; ++q)
#pragma unroll
    for (int r = 0; r < 16; ++r) acc[q][r] = 0.f;

  const unsigned int* mkw = mkpl + ks * 512;
  for (int ch = 0; ch < NCH; ++ch) {
    int cur = ch & 1;
    if (ch + 1 < NCH)
      gload16(wsrc0 + (ch + 1) * 32, smem + (cur ^ 1) * 8192 + t * 16);
    char* wb = smem + cur * 8192;
    int jb = ch * 32 + jh * 16 + hl * 8;
    // 8 mask words + 8 st2 pairs: wave-uniform vector LDS reads
    uint4v mw0 = *(const uint4v*)(mkw + jb);
    uint4v mw1 = *(const uint4v*)(mkw + jb + 4);
    short8 af;
#pragma unroll
    for (int e = 0; e < 8; ++e) {
      float2 sc = stl[jb + e];
      unsigned mv = (e < 4) ? mw0[e] : mw1[e - 4];
      float e1 = sc.x + z1;
      float e2 = sc.y + z2;
      float p = exp2f(fmaxf(e1, e2));
      int msk = ((int)(mv << sh31)) >> 31;
      unsigned pu = __float_as_uint(p) & (unsigned)msk;
      __hip_bfloat16 hb = __float2bfloat16(__uint_as_float(pu));
      af[e] = *(short*)&hb;
    }
    int gb = (jh * 2 + hl) * 2048;
#pragma unroll
    for (int q = 0; q < 4; ++q) {
      short8 bv = *(const short8*)(wb + gb + ((q * 32 + ln) << 4));
      acc[q] = __builtin_amdgcn_mfma_f32_32x32x16_bf16(af, bv, acc[q], 0, 0, 0);
    }
    __syncthreads();
  }

  // jh-merge via bf16 zone (aliases smem), then slab store
  unsigned short* zone = (unsigned short*)smem;
  if (jh == 1) {
#pragma unroll
    for (int q = 0; q < 4; ++q)
#pragma unroll
      for (int r = 0; r < 16; ++r) {
        int kl = (r & 3) + ((r >> 2) << 3) + (hl << 2);
        zone[ks * 4096 + q * 1024 + kl * 32 + ln] = f2bf(acc[q][r]);
      }
  }
  __syncthreads();
  if (jh == 0) {
    long long rbase = (brow + k0) << 7;
    unsigned short* pb = pbuf + (long long)jc * SLAB + rbase;
#pragma unroll
    for (int q = 0; q < 4; ++q)
#pragma unroll
      for (int r = 0; r < 16; ++r) {
        int kl = (r & 3) + ((r >> 2) << 3) + (hl << 2);
        float v = acc[q][r] + bf2f(zone[ks * 4096 + q * 1024 + kl * 32 + ln]);
        pb[(ks * 32 + kl) * 128 + q * 32 + ln] = f2bf(v);
      }
  }
}

// ---------------------------------------------------------------------------
// k4: out = elu(sum_jc bf16 partial). Grid 1024 x 256, 8 elems/thread.
// Swizzle reads tile m from the XCD (m>>4) where k3 wrote it (L2-local).
// ---------------------------------------------------------------------------
__global__ __launch_bounds__(256) void k4_reduce(
    const unsigned short* __restrict__ pbuf, float* __restrict__ out) {
  int orig = blockIdx.x;
  int n = (orig & 7) * 128 + (orig >> 3);  // bijective (1024 % 8 == 0)
  int base = (n * 256 + threadIdx.x) * 8;
  float s[8] = {0.f, 0.f, 0.f, 0.f, 0.f, 0.f, 0.f, 0.f};
#pragma unroll
  for (int sl = 0; sl < JC; ++sl) {
    ushort8 v = *(const ushort8*)(pbuf + (long long)sl * SLAB + base);
#pragma unroll
    for (int e = 0; e < 8; ++e)
      s[e] += __uint_as_float(((unsigned)(unsigned short)v[e]) << 16);
  }
  f32x4 o0, o1;
#pragma unroll
  for (int e = 0; e < 8; ++e) {
    float xv = s[e];
    float y = xv > 0.f ? xv : expm1f(xv);
    if (e < 4) o0[e] = y; else o1[e - 4] = y;
  }
  *(f32x4*)(out + base) = o0;
  *(f32x4*)(out + base + 4) = o1;
}

extern "C" void kernel_launch(void* const* d_in, const int* in_sizes, int n_in,
                              void* d_out, int out_size, void* d_ws,
                              size_t ws_size, hipStream_t stream) {
  const float* h = (const float*)d_in[0];
  const int* adj = (const int*)d_in[1];
  const float* W = (const float*)d_in[2];
  const float* a = (const float*)d_in[3];
  float* out = (float*)d_out;

  char* ws = (char*)d_ws;
  unsigned short* WT = (unsigned short*)ws;                  // 64 KB
  unsigned short* whT = (unsigned short*)(ws + (1 << 20));   // 4 MB
  float* s1L = (float*)(ws + (5 << 20));                     // 64 KB
  float* s2L = s1L + 16384;                                  // 64 KB
  float2* st2 = (float2*)(ws + (5 << 20) + (128 << 10));     // 128 KB
  unsigned long long* mask64 =
      (unsigned long long*)(ws + (6 << 20));                 // 8 MB
  unsigned short* pbuf = (unsigned short*)(ws + (16 << 20)); // 32 MB bf16

  hipLaunchKernelGGL(k0_prep, dim3(8), dim3(256), 0, stream, W, WT);
  hipLaunchKernelGGL(k1b_wh, dim3(1024), dim3(256), 0, stream, h, WT, a, whT,
                     s1L, s2L);
  hipLaunchKernelGGL(k2_stats, dim3(8192), dim3(256), 0, stream, adj, s1L,
                     s2L, st2, mask64);
  hipLaunchKernelGGL(k3_pv, dim3(1024), dim3(512), 0, stream, whT, st2,
                     mask64, s2L, pbuf);
  hipLaunchKernelGGL(k4_reduce, dim3(1024), dim3(256), 0, stream, pbuf, out);
}

// Round 12
// 121.309 us; speedup vs baseline: 8.6877x; 1.0710x over previous
//
#include <hip/hip_runtime.h>
#include <hip/hip_bf16.h>

#define ALPHA 0.2f
#define L2E 1.4426950408889634f

constexpr int Nn = 4096;
constexpr int FIN = 256;
constexpr int FOUT = 128;
constexpr int JC = 8;    // j-split for k3
constexpr int JQ = 512;  // j per k3 block
constexpr int NCH = 16;  // 32-j chunks per k3 block
constexpr long long SLAB = 2097152;  // 4*4096*128 elems per partial slab

typedef __attribute__((ext_vector_type(8))) short short8;
typedef __attribute__((ext_vector_type(8))) unsigned short ushort8;
typedef __attribute__((ext_vector_type(4))) float f32x4;
typedef __attribute__((ext_vector_type(4))) int int4v;
typedef __attribute__((ext_vector_type(4))) unsigned int uint4v;

__device__ __forceinline__ unsigned short f2bf(float x) {
  unsigned int u = __float_as_uint(x);
  unsigned int r = (u + 0x7fffu + ((u >> 16) & 1u)) >> 16;
  return (unsigned short)r;
}

__device__ __forceinline__ float bf2f(unsigned short v) {
  return __uint_as_float(((unsigned)v) << 16);
}

__device__ __forceinline__ void gload16(const void* g, void* l) {
  auto lp = (__attribute__((address_space(3))) void*)l;
  auto gp = (const __attribute__((address_space(1))) void*)g;
  __builtin_amdgcn_global_load_lds(gp, lp, 16, 0, 0);
}

// ---------------------------------------------------------------------------
// k0: WT bf16 [i=128][k=256] from W f32 [k][i] (LDS transpose). Grid 8.
// ---------------------------------------------------------------------------
__global__ __launch_bounds__(256) void k0_prep(
    const float* __restrict__ W, unsigned short* __restrict__ WT) {
  __shared__ float lw[32][132];
  int t = threadIdx.x;
  int kc0 = blockIdx.x * 32;
#pragma unroll
  for (int m = 0; m < 4; ++m) {
    int idx = t * 16 + m * 4;
    f32x4 v = *(const f32x4*)(W + kc0 * 128 + idx);
    int k = idx >> 7, i0 = idx & 127;
    *(f32x4*)&lw[k][i0] = v;
  }
  __syncthreads();
  int i = t >> 1, half = t & 1;
  unsigned short pk[16];
#pragma unroll
  for (int kk = 0; kk < 16; ++kk) pk[kk] = f2bf(lw[half * 16 + kk][i]);
  ushort8* dst = (ushort8*)(WT + i * 256 + kc0 + half * 16);
  dst[0] = *(ushort8*)&pk[0];
  dst[1] = *(ushort8*)&pk[8];
}

// ---------------------------------------------------------------------------
// k1b: Wh via mfma_16x16x32_bf16. 16-row blocks, grid 1024.
// Emits whT bf16 [b][i=128][n=4096] AND s1L/s2L (x log2 e).
// ---------------------------------------------------------------------------
__global__ __launch_bounds__(256) void k1b_wh(
    const float* __restrict__ h, const unsigned short* __restrict__ WT,
    const float* __restrict__ a, unsigned short* __restrict__ whT,
    float* __restrict__ s1L, float* __restrict__ s2L) {
  __shared__ __align__(16) char smem[36864];
  int t = threadIdx.x;
  int w = t >> 6, l = t & 63, g = l >> 4, r = l & 15;
  int r0 = blockIdx.x * 16;
  int b = r0 >> 12, nbase = r0 & 4095;

  f32x4 acc[2];
  acc[0] = (f32x4){0.f, 0.f, 0.f, 0.f};
  acc[1] = (f32x4){0.f, 0.f, 0.f, 0.f};

  for (int kc = 0; kc < 2; ++kc) {
    __syncthreads();
    {
      int row = t >> 4, sec = t & 15;
      const f32x4* src =
          (const f32x4*)(h + (long long)(r0 + row) * 256 + kc * 128 + sec * 8);
      f32x4 v0 = src[0], v1 = src[1];
      unsigned int pk[4];
      pk[0] = ((unsigned)f2bf(v0.y) << 16) | f2bf(v0.x);
      pk[1] = ((unsigned)f2bf(v0.w) << 16) | f2bf(v0.z);
      pk[2] = ((unsigned)f2bf(v1.y) << 16) | f2bf(v1.x);
      pk[3] = ((unsigned)f2bf(v1.w) << 16) | f2bf(v1.z);
      *(ushort8*)(smem + row * 256 + ((sec ^ (row & 7)) << 4)) = *(ushort8*)pk;
    }
    {
      int i = t >> 1, pt = t & 1;
      const ushort8* src = (const ushort8*)(WT + i * 256 + kc * 128 + pt * 64);
#pragma unroll
      for (int m = 0; m < 8; ++m) {
        ushort8 v = src[m];
        int slot = pt * 8 + m;
        *(ushort8*)(smem + 4096 + i * 256 + ((slot ^ (i & 7)) << 4)) = v;
      }
    }
    __syncthreads();
#pragma unroll
    for (int kk = 0; kk < 4; ++kk) {
      short8 af =
          *(const short8*)(smem + r * 256 + (((kk * 4 + g) ^ (r & 7)) << 4));
#pragma unroll
      for (int s = 0; s < 2; ++s) {
        int i = w * 32 + s * 16 + r;
        short8 bf = *(const short8*)(smem + 4096 + i * 256 +
                                     (((kk * 4 + g) ^ (i & 7)) << 4));
        acc[s] =
            __builtin_amdgcn_mfma_f32_16x16x32_bf16(af, bf, acc[s], 0, 0, 0);
      }
    }
  }

  __syncthreads();
  unsigned short* tb = (unsigned short*)smem;  // [128][25]
#pragma unroll
  for (int s = 0; s < 2; ++s)
#pragma unroll
    for (int q = 0; q < 4; ++q)
      tb[(w * 32 + s * 16 + r) * 25 + g * 4 + q] = f2bf(acc[s][q]);
  __syncthreads();

  {
    int i = t >> 1, half = t & 1;
    ushort8 v = *(const ushort8*)(tb + i * 25 + half * 8);
    *(ushort8*)(whT + (((long long)(b * 128 + i)) << 12) + nbase + half * 8) =
        v;
  }
  {
    int n = t >> 4, seg = t & 15;
    f32x4 a10 = *(const f32x4*)(a + seg * 8);
    f32x4 a11 = *(const f32x4*)(a + seg * 8 + 4);
    f32x4 a20 = *(const f32x4*)(a + 128 + seg * 8);
    f32x4 a21 = *(const f32x4*)(a + 128 + seg * 8 + 4);
    float v1 = 0.f, v2 = 0.f;
#pragma unroll
    for (int m = 0; m < 8; ++m) {
      float wh = bf2f(tb[(seg * 8 + m) * 25 + n]);
      float c1 = (m < 4) ? a10[m] : a11[m - 4];
      float c2 = (m < 4) ? a20[m] : a21[m - 4];
      v1 += wh * c1;
      v2 += wh * c2;
    }
#pragma unroll
    for (int off = 8; off; off >>= 1) {
      v1 += __shfl_xor(v1, off);
      v2 += __shfl_xor(v2, off);
    }
    if (seg == 0) {
      s1L[r0 + n] = v1 * L2E;
      s2L[r0 + n] = v2 * L2E;
    }
  }
}

// ---------------------------------------------------------------------------
// k2: block-per-row, coalesced NT int4 adj loads, single-pass no-max softmax
// in exp2 domain; mask via shfl_xor nibble merge. st2[row] = {s1L + negc,
// ALPHA*s1L + negc}; mask64[row][64]. Grid 16384 x 256. (R6 form, ~45us.)
// ---------------------------------------------------------------------------
__global__ __launch_bounds__(256) void k2_stats(
    const int* __restrict__ adj, const float* __restrict__ s1L,
    const float* __restrict__ s2L, float2* __restrict__ st2,
    unsigned long long* __restrict__ mask64) {
  __shared__ unsigned int mwords[128];
  __shared__ float wsum[4];
  int row = blockIdx.x;
  int b = row >> 12;
  int t = threadIdx.x;
  float s1j = s1L[row];
  const int4v* arow = (const int4v*)(adj + (long long)row * Nn);
  const f32x4* s2v = (const f32x4*)(s2L + (b << 12));

  float sum = 0.f;
#pragma unroll
  for (int q = 0; q < 4; ++q) {
    int4v av = __builtin_nontemporal_load(arow + q * 256 + t);
    f32x4 sv = s2v[q * 256 + t];
    unsigned nib = 0;
#pragma unroll
    for (int c = 0; c < 4; ++c) {
      float u = s1j + sv[c];
      float vL = fmaxf(u, ALPHA * u);
      float e = exp2f(vL);
      sum = fmaf((float)av[c], e, sum);  // adj in {0,1}
      nib |= ((unsigned)av[c]) << c;
    }
    unsigned n1 = nib | (__shfl_xor(nib, 1) << 4);
    unsigned n2 = n1 | (__shfl_xor(n1, 2) << 8);
    unsigned n4 = n2 | (__shfl_xor(n2, 4) << 16);
    if ((t & 7) == 0) mwords[q * 32 + (t >> 3)] = n4;
  }
#pragma unroll
  for (int off = 32; off; off >>= 1) sum += __shfl_xor(sum, off);
  if ((t & 63) == 0) wsum[t >> 6] = sum;
  __syncthreads();
  if (t < 64) {
    unsigned long long mv = *(unsigned long long*)&mwords[t * 2];
    mask64[((long long)row << 6) + t] = mv;
  }
  if (t == 0) {
    float S = wsum[0] + wsum[1] + wsum[2] + wsum[3];
    float negc = (S > 0.f) ? -log2f(S) : -1.0e30f;
    st2[row] = make_float2(s1j + negc, ALPHA * s1j + negc);
  }
}

// ---------------------------------------------------------------------------
// k3: bf16 partial[jc][b][k][i] = sum_{j in eighth} p[j,k]*Wh[j,i].
// 16x16x32 MFMA => acc 32 VGPR (was 64) => 6 waves/SIMD (was 4).
// Grid 1024 = 4b x 8jc x 32kt; x=orig&7 -> (b, kt>>4): all 8 jc of a (b,kt)
// share one XCD. 512 thr = 8 waves = 8 k-subs of 16 (KT=128); each wave does
// full i=128 (8 i-tiles), one A-frag per 32-j chunk feeds 8 MFMAs.
// LDS 28KB: whT dbuf 2x8K @0 (granule gj*128+gi, measured 0-conflict family),
// mask u32 planes mk[4][512] @16K (plane = k_local>>5 = ks>>1), stl @24K.
// ---------------------------------------------------------------------------
__global__ __launch_bounds__(512, 6) void k3_pv(
    const unsigned short* __restrict__ whT, const float2* __restrict__ st2,
    const unsigned long long* __restrict__ mask64,
    const float* __restrict__ s2L, unsigned short* __restrict__ pbuf) {
  __shared__ __align__(16) char smem[28672];
  unsigned int* mkpl = (unsigned int*)(smem + 16384);  // [4][512]
  float2* stl = (float2*)(smem + 24576);               // [512]

  int t = threadIdx.x;
  int orig = blockIdx.x;
  int x = orig & 7, mm = orig >> 3;
  int b = x >> 1;
  int kt = ((x & 1) << 4) | (mm & 15);  // 0..31
  int jc = mm >> 4;                     // 0..7
  int w = t >> 6, l = t & 63;
  int lh = l >> 4;   // 0..3: j-subgroup (A/B K-group)
  int lo = l & 15;   // 0..15: A-row (k) / B-col (i)
  int ks = w;        // 8 k-subs x 16
  int jq0 = jc * JQ;
  long long brow = (long long)(b << 12);
  int k0g = kt << 7;  // KT = 128
  float z1 = s2L[brow + k0g + ks * 16 + lo];
  float z2 = ALPHA * z1;
  int sh31 = 31 - (((ks & 1) << 4) + lo);
  int wsel = ks >> 1;  // u32 mask plane

  // stage-once: stl (4KB via gload16), mask planes (reg-staged scatter)
  if (t < 256) gload16(st2 + brow + jq0 + t * 2, (char*)stl + t * 16);
  {
    uint4v mrow = *(const uint4v*)((const char*)(mask64 +
                                                 ((brow + jq0 + t) << 6)) +
                                   kt * 16);
    mkpl[0 * 512 + t] = mrow[0];
    mkpl[1 * 512 + t] = mrow[1];
    mkpl[2 * 512 + t] = mrow[2];
    mkpl[3 * 512 + t] = mrow[3];
  }
  // whT chunk 0: thread t -> granule (gj=t>>7 j-oct, gi=t&127 i), linear dest
  const unsigned short* whTb = whT + ((long long)b << 19);
  int gi = t & 127;
  const unsigned short* wsrc0 =
      whTb + (long long)gi * 4096 + jq0 + (t >> 7) * 8;
  gload16(wsrc0, smem + t * 16);
  __syncthreads();

  f32x4 acc[8];
#pragma unroll
  for (int q = 0; q < 8; ++q) acc[q] = (f32x4){0.f, 0.f, 0.f, 0.f};

  const unsigned int* mkw = mkpl + wsel * 512;
  for (int ch = 0; ch < NCH; ++ch) {
    int cur = ch & 1;
    if (ch + 1 < NCH)
      gload16(wsrc0 + (ch + 1) * 32, smem + (cur ^ 1) * 8192 + t * 16);
    char* wb = smem + cur * 8192;
    int jb = ch * 32 + lh * 8;  // this lane-group's 8 j's
    uint4v mw0 = *(const uint4v*)(mkw + jb);
    uint4v mw1 = *(const uint4v*)(mkw + jb + 4);
    short8 af;
#pragma unroll
    for (int e = 0; e < 8; ++e) {
      float2 sc = stl[jb + e];
      unsigned mv = (e < 4) ? mw0[e] : mw1[e - 4];
      float e1 = sc.x + z1;
      float e2 = sc.y + z2;
      float p = exp2f(fmaxf(e1, e2));
      int msk = ((int)(mv << sh31)) >> 31;
      unsigned pu = __float_as_uint(p) & (unsigned)msk;
      __hip_bfloat16 hb = __float2bfloat16(__uint_as_float(pu));
      af[e] = *(short*)&hb;
    }
#pragma unroll
    for (int q = 0; q < 8; ++q) {
      short8 bv = *(const short8*)(wb + ((lh * 128 + q * 16 + lo) << 4));
      acc[q] = __builtin_amdgcn_mfma_f32_16x16x32_bf16(af, bv, acc[q], 0, 0, 0);
    }
    __syncthreads();
  }

  // store: D col = lo (i within tile), row = lh*4 + r (k within 16)
  unsigned short* pb = pbuf + (long long)jc * SLAB + ((brow + k0g) << 7);
#pragma unroll
  for (int q = 0; q < 8; ++q) {
#pragma unroll
    for (int r = 0; r < 4; ++r) {
      int kl = ks * 16 + lh * 4 + r;
      pb[kl * 128 + q * 16 + lo] = f2bf(acc[q][r]);
    }
  }
}

// ---------------------------------------------------------------------------
// k4: out = elu(sum_jc bf16 partial). Grid 1024 x 256, 8 elems/thread.
// Swizzle reads tile n from the XCD (n>>7) where k3 wrote it.
// ---------------------------------------------------------------------------
__global__ __launch_bounds__(256) void k4_reduce(
    const unsigned short* __restrict__ pbuf, float* __restrict__ out) {
  int orig = blockIdx.x;
  int n = (orig & 7) * 128 + (orig >> 3);  // bijective (1024 % 8 == 0)
  int base = (n * 256 + threadIdx.x) * 8;
  float s[8] = {0.f, 0.f, 0.f, 0.f, 0.f, 0.f, 0.f, 0.f};
#pragma unroll
  for (int sl = 0; sl < JC; ++sl) {
    ushort8 v = *(const ushort8*)(pbuf + (long long)sl * SLAB + base);
#pragma unroll
    for (int e = 0; e < 8; ++e)
      s[e] += __uint_as_float(((unsigned)(unsigned short)v[e]) << 16);
  }
  f32x4 o0, o1;
#pragma unroll
  for (int e = 0; e < 8; ++e) {
    float xv = s[e];
    float y = xv > 0.f ? xv : expm1f(xv);
    if (e < 4) o0[e] = y; else o1[e - 4] = y;
  }
  *(f32x4*)(out + base) = o0;
  *(f32x4*)(out + base + 4) = o1;
}

extern "C" void kernel_launch(void* const* d_in, const int* in_sizes, int n_in,
                              void* d_out, int out_size, void* d_ws,
                              size_t ws_size, hipStream_t stream) {
  const float* h = (const float*)d_in[0];
  const int* adj = (const int*)d_in[1];
  const float* W = (const float*)d_in[2];
  const float* a = (const float*)d_in[3];
  float* out = (float*)d_out;

  char* ws = (char*)d_ws;
  unsigned short* WT = (unsigned short*)ws;                  // 64 KB
  unsigned short* whT = (unsigned short*)(ws + (1 << 20));   // 4 MB
  float* s1L = (float*)(ws + (5 << 20));                     // 64 KB
  float* s2L = s1L + 16384;                                  // 64 KB
  float2* st2 = (float2*)(ws + (5 << 20) + (128 << 10));     // 128 KB
  unsigned long long* mask64 =
      (unsigned long long*)(ws + (6 << 20));                 // 8 MB
  unsigned short* pbuf = (unsigned short*)(ws + (16 << 20)); // 32 MB bf16

  hipLaunchKernelGGL(k0_prep, dim3(8), dim3(256), 0, stream, W, WT);
  hipLaunchKernelGGL(k1b_wh, dim3(1024), dim3(256), 0, stream, h, WT, a, whT,
                     s1L, s2L);
  hipLaunchKernelGGL(k2_stats, dim3(16384), dim3(256), 0, stream, adj, s1L,
                     s2L, st2, mask64);
  hipLaunchKernelGGL(k3_pv, dim3(1024), dim3(512), 0, stream, whT, st2,
                     mask64, s2L, pbuf);
  hipLaunchKernelGGL(k4_reduce, dim3(1024), dim3(256), 0, stream, pbuf, out);
}

// Round 13
// 109.462 us; speedup vs baseline: 9.6279x; 1.1082x over previous
//
#include <hip/hip_runtime.h>
#include <hip/hip_bf16.h>

#define ALPHA 0.2f
#define L2E 1.4426950408889634f

constexpr int Nn = 4096;
constexpr int FIN = 256;
constexpr int FOUT = 128;
constexpr int JC = 8;    // j-split for k3
constexpr int JQ = 512;  // j per k3 block
constexpr int NCH = 16;  // 32-j chunks per k3 block
constexpr long long SLAB = 2097152;  // 4*4096*128 elems per partial slab

typedef __attribute__((ext_vector_type(8))) short short8;
typedef __attribute__((ext_vector_type(8))) unsigned short ushort8;
typedef __attribute__((ext_vector_type(4))) float f32x4;
typedef __attribute__((ext_vector_type(4))) int int4v;
typedef __attribute__((ext_vector_type(4))) unsigned int uint4v;

__device__ __forceinline__ unsigned short f2bf(float x) {
  unsigned int u = __float_as_uint(x);
  unsigned int r = (u + 0x7fffu + ((u >> 16) & 1u)) >> 16;
  return (unsigned short)r;
}

__device__ __forceinline__ float bf2f(unsigned short v) {
  return __uint_as_float(((unsigned)v) << 16);
}

__device__ __forceinline__ void gload16(const void* g, void* l) {
  auto lp = (__attribute__((address_space(3))) void*)l;
  auto gp = (const __attribute__((address_space(1))) void*)g;
  __builtin_amdgcn_global_load_lds(gp, lp, 16, 0, 0);
}

// ---------------------------------------------------------------------------
// k0: WT bf16 [i=128][k=256] from W f32 [k][i] (LDS transpose). Grid 8.
// ---------------------------------------------------------------------------
__global__ __launch_bounds__(256) void k0_prep(
    const float* __restrict__ W, unsigned short* __restrict__ WT) {
  __shared__ float lw[32][132];
  int t = threadIdx.x;
  int kc0 = blockIdx.x * 32;
#pragma unroll
  for (int m = 0; m < 4; ++m) {
    int idx = t * 16 + m * 4;
    f32x4 v = *(const f32x4*)(W + kc0 * 128 + idx);
    int k = idx >> 7, i0 = idx & 127;
    *(f32x4*)&lw[k][i0] = v;
  }
  __syncthreads();
  int i = t >> 1, half = t & 1;
  unsigned short pk[16];
#pragma unroll
  for (int kk = 0; kk < 16; ++kk) pk[kk] = f2bf(lw[half * 16 + kk][i]);
  ushort8* dst = (ushort8*)(WT + i * 256 + kc0 + half * 16);
  dst[0] = *(ushort8*)&pk[0];
  dst[1] = *(ushort8*)&pk[8];
}

// ---------------------------------------------------------------------------
// k1b: Wh via mfma_16x16x32_bf16. 16-row blocks, grid 1024.
// Emits whT bf16 [b][i=128][n=4096] AND s1L/s2L (x log2 e).
// ---------------------------------------------------------------------------
__global__ __launch_bounds__(256) void k1b_wh(
    const float* __restrict__ h, const unsigned short* __restrict__ WT,
    const float* __restrict__ a, unsigned short* __restrict__ whT,
    float* __restrict__ s1L, float* __restrict__ s2L) {
  __shared__ __align__(16) char smem[36864];
  int t = threadIdx.x;
  int w = t >> 6, l = t & 63, g = l >> 4, r = l & 15;
  int r0 = blockIdx.x * 16;
  int b = r0 >> 12, nbase = r0 & 4095;

  f32x4 acc[2];
  acc[0] = (f32x4){0.f, 0.f, 0.f, 0.f};
  acc[1] = (f32x4){0.f, 0.f, 0.f, 0.f};

  for (int kc = 0; kc < 2; ++kc) {
    __syncthreads();
    {
      int row = t >> 4, sec = t & 15;
      const f32x4* src =
          (const f32x4*)(h + (long long)(r0 + row) * 256 + kc * 128 + sec * 8);
      f32x4 v0 = src[0], v1 = src[1];
      unsigned int pk[4];
      pk[0] = ((unsigned)f2bf(v0.y) << 16) | f2bf(v0.x);
      pk[1] = ((unsigned)f2bf(v0.w) << 16) | f2bf(v0.z);
      pk[2] = ((unsigned)f2bf(v1.y) << 16) | f2bf(v1.x);
      pk[3] = ((unsigned)f2bf(v1.w) << 16) | f2bf(v1.z);
      *(ushort8*)(smem + row * 256 + ((sec ^ (row & 7)) << 4)) = *(ushort8*)pk;
    }
    {
      int i = t >> 1, pt = t & 1;
      const ushort8* src = (const ushort8*)(WT + i * 256 + kc * 128 + pt * 64);
#pragma unroll
      for (int m = 0; m < 8; ++m) {
        ushort8 v = src[m];
        int slot = pt * 8 + m;
        *(ushort8*)(smem + 4096 + i * 256 + ((slot ^ (i & 7)) << 4)) = v;
      }
    }
    __syncthreads();
#pragma unroll
    for (int kk = 0; kk < 4; ++kk) {
      short8 af =
          *(const short8*)(smem + r * 256 + (((kk * 4 + g) ^ (r & 7)) << 4));
#pragma unroll
      for (int s = 0; s < 2; ++s) {
        int i = w * 32 + s * 16 + r;
        short8 bf = *(const short8*)(smem + 4096 + i * 256 +
                                     (((kk * 4 + g) ^ (i & 7)) << 4));
        acc[s] =
            __builtin_amdgcn_mfma_f32_16x16x32_bf16(af, bf, acc[s], 0, 0, 0);
      }
    }
  }

  __syncthreads();
  unsigned short* tb = (unsigned short*)smem;  // [128][25]
#pragma unroll
  for (int s = 0; s < 2; ++s)
#pragma unroll
    for (int q = 0; q < 4; ++q)
      tb[(w * 32 + s * 16 + r) * 25 + g * 4 + q] = f2bf(acc[s][q]);
  __syncthreads();

  {
    int i = t >> 1, half = t & 1;
    ushort8 v = *(const ushort8*)(tb + i * 25 + half * 8);
    *(ushort8*)(whT + (((long long)(b * 128 + i)) << 12) + nbase + half * 8) =
        v;
  }
  {
    int n = t >> 4, seg = t & 15;
    f32x4 a10 = *(const f32x4*)(a + seg * 8);
    f32x4 a11 = *(const f32x4*)(a + seg * 8 + 4);
    f32x4 a20 = *(const f32x4*)(a + 128 + seg * 8);
    f32x4 a21 = *(const f32x4*)(a + 128 + seg * 8 + 4);
    float v1 = 0.f, v2 = 0.f;
#pragma unroll
    for (int m = 0; m < 8; ++m) {
      float wh = bf2f(tb[(seg * 8 + m) * 25 + n]);
      float c1 = (m < 4) ? a10[m] : a11[m - 4];
      float c2 = (m < 4) ? a20[m] : a21[m - 4];
      v1 += wh * c1;
      v2 += wh * c2;
    }
#pragma unroll
    for (int off = 8; off; off >>= 1) {
      v1 += __shfl_xor(v1, off);
      v2 += __shfl_xor(v2, off);
    }
    if (seg == 0) {
      s1L[r0 + n] = v1 * L2E;
      s2L[r0 + n] = v2 * L2E;
    }
  }
}

// ---------------------------------------------------------------------------
// k2: block-per-row, coalesced NT int4 adj loads, single-pass no-max softmax
// in exp2 domain; mask via shfl_xor nibble merge. st2[row] = {E1, E2} where
// E1 = exp2(s1L+negc), E2 = exp2(ALPHA*s1L+negc) -- factorized for k3
// (p = max(E1*F1, E2*F2), exp2 removed from the 67M-element hot path).
// ---------------------------------------------------------------------------
__global__ __launch_bounds__(256) void k2_stats(
    const int* __restrict__ adj, const float* __restrict__ s1L,
    const float* __restrict__ s2L, float2* __restrict__ st2,
    unsigned long long* __restrict__ mask64) {
  __shared__ unsigned int mwords[128];
  __shared__ float wsum[4];
  int row = blockIdx.x;
  int b = row >> 12;
  int t = threadIdx.x;
  float s1j = s1L[row];
  const int4v* arow = (const int4v*)(adj + (long long)row * Nn);
  const f32x4* s2v = (const f32x4*)(s2L + (b << 12));

  float sum = 0.f;
#pragma unroll
  for (int q = 0; q < 4; ++q) {
    int4v av = __builtin_nontemporal_load(arow + q * 256 + t);
    f32x4 sv = s2v[q * 256 + t];
    unsigned nib = 0;
#pragma unroll
    for (int c = 0; c < 4; ++c) {
      float u = s1j + sv[c];
      float vL = fmaxf(u, ALPHA * u);
      float e = exp2f(vL);
      sum = fmaf((float)av[c], e, sum);  // adj in {0,1}
      nib |= ((unsigned)av[c]) << c;
    }
    unsigned n1 = nib | (__shfl_xor(nib, 1) << 4);
    unsigned n2 = n1 | (__shfl_xor(n1, 2) << 8);
    unsigned n4 = n2 | (__shfl_xor(n2, 4) << 16);
    if ((t & 7) == 0) mwords[q * 32 + (t >> 3)] = n4;
  }
#pragma unroll
  for (int off = 32; off; off >>= 1) sum += __shfl_xor(sum, off);
  if ((t & 63) == 0) wsum[t >> 6] = sum;
  __syncthreads();
  if (t < 64) {
    unsigned long long mv = *(unsigned long long*)&mwords[t * 2];
    mask64[((long long)row << 6) + t] = mv;
  }
  if (t == 0) {
    float S = wsum[0] + wsum[1] + wsum[2] + wsum[3];
    float negc = (S > 0.f) ? -log2f(S) : -1.0e30f;
    st2[row] =
        make_float2(exp2f(s1j + negc), exp2f(ALPHA * s1j + negc));
  }
}

// ---------------------------------------------------------------------------
// k3: bf16 partial[jc][b][k][i] = sum_{j in eighth} p[j,k]*Wh[j,i].
// A-build factorized: p = max(E1_j*F1_k, E2_j*F2_k), masked -- 2 mul + max
// + 3 bit-ops + cvt per element (exp2/adds removed; ~30% of the measured
// 31us VALU floor). 16x16x32 MFMA, grid 1024 = 4b x 8jc x 32kt.
// LDS 28KB: whT dbuf 2x8K @0, mask planes mk[4][512] @16K, stl {E1,E2} @24K.
// ---------------------------------------------------------------------------
__global__ __launch_bounds__(512, 6) void k3_pv(
    const unsigned short* __restrict__ whT, const float2* __restrict__ st2,
    const unsigned long long* __restrict__ mask64,
    const float* __restrict__ s2L, unsigned short* __restrict__ pbuf) {
  __shared__ __align__(16) char smem[28672];
  unsigned int* mkpl = (unsigned int*)(smem + 16384);  // [4][512]
  float2* stl = (float2*)(smem + 24576);               // [512]

  int t = threadIdx.x;
  int orig = blockIdx.x;
  int x = orig & 7, mm = orig >> 3;
  int b = x >> 1;
  int kt = ((x & 1) << 4) | (mm & 15);  // 0..31
  int jc = mm >> 4;                     // 0..7
  int w = t >> 6, l = t & 63;
  int lh = l >> 4;   // 0..3: j-subgroup (A/B K-group)
  int lo = l & 15;   // 0..15: A-row (k) / B-col (i)
  int ks = w;        // 8 k-subs x 16
  int jq0 = jc * JQ;
  long long brow = (long long)(b << 12);
  int k0g = kt << 7;  // KT = 128
  float z1 = s2L[brow + k0g + ks * 16 + lo];
  float F1 = exp2f(z1);
  float F2 = exp2f(ALPHA * z1);
  int sh31 = 31 - (((ks & 1) << 4) + lo);
  int wsel = ks >> 1;  // u32 mask plane

  // stage-once: stl (4KB via gload16), mask planes (reg-staged scatter)
  if (t < 256) gload16(st2 + brow + jq0 + t * 2, (char*)stl + t * 16);
  {
    uint4v mrow = *(const uint4v*)((const char*)(mask64 +
                                                 ((brow + jq0 + t) << 6)) +
                                   kt * 16);
    mkpl[0 * 512 + t] = mrow[0];
    mkpl[1 * 512 + t] = mrow[1];
    mkpl[2 * 512 + t] = mrow[2];
    mkpl[3 * 512 + t] = mrow[3];
  }
  // whT chunk 0: thread t -> granule (gj=t>>7 j-oct, gi=t&127 i), linear dest
  const unsigned short* whTb = whT + ((long long)b << 19);
  int gi = t & 127;
  const unsigned short* wsrc0 =
      whTb + (long long)gi * 4096 + jq0 + (t >> 7) * 8;
  gload16(wsrc0, smem + t * 16);
  __syncthreads();

  f32x4 acc[8];
#pragma unroll
  for (int q = 0; q < 8; ++q) acc[q] = (f32x4){0.f, 0.f, 0.f, 0.f};

  const unsigned int* mkw = mkpl + wsel * 512;
  for (int ch = 0; ch < NCH; ++ch) {
    int cur = ch & 1;
    if (ch + 1 < NCH)
      gload16(wsrc0 + (ch + 1) * 32, smem + (cur ^ 1) * 8192 + t * 16);
    char* wb = smem + cur * 8192;
    int jb = ch * 32 + lh * 8;  // this lane-group's 8 j's
    uint4v mw0 = *(const uint4v*)(mkw + jb);
    uint4v mw1 = *(const uint4v*)(mkw + jb + 4);
    const f32x4* stp = (const f32x4*)(stl + jb);  // 16B-aligned (jb even)
    f32x4 sA = stp[0], sB = stp[1], sC = stp[2], sD = stp[3];
    short8 af;
#pragma unroll
    for (int e = 0; e < 8; ++e) {
      f32x4 sv = (e < 2) ? sA : (e < 4) ? sB : (e < 6) ? sC : sD;
      float E1 = (e & 1) ? sv.z : sv.x;
      float E2 = (e & 1) ? sv.w : sv.y;
      unsigned mv = (e < 4) ? mw0[e] : mw1[e - 4];
      float p = fmaxf(E1 * F1, E2 * F2);
      int msk = ((int)(mv << sh31)) >> 31;
      unsigned pu = __float_as_uint(p) & (unsigned)msk;
      __hip_bfloat16 hb = __float2bfloat16(__uint_as_float(pu));
      af[e] = *(short*)&hb;
    }
#pragma unroll
    for (int q = 0; q < 8; ++q) {
      short8 bv = *(const short8*)(wb + ((lh * 128 + q * 16 + lo) << 4));
      acc[q] = __builtin_amdgcn_mfma_f32_16x16x32_bf16(af, bv, acc[q], 0, 0, 0);
    }
    __syncthreads();
  }

  // store: D col = lo (i within tile), row = lh*4 + r (k within 16)
  unsigned short* pb = pbuf + (long long)jc * SLAB + ((brow + k0g) << 7);
#pragma unroll
  for (int q = 0; q < 8; ++q) {
#pragma unroll
    for (int r = 0; r < 4; ++r) {
      int kl = ks * 16 + lh * 4 + r;
      pb[kl * 128 + q * 16 + lo] = f2bf(acc[q][r]);
    }
  }
}

// ---------------------------------------------------------------------------
// k4: out = elu(sum_jc bf16 partial). Grid 1024 x 256, 8 elems/thread.
// Swizzle reads tile n from the XCD (n>>7) where k3 wrote it.
// ---------------------------------------------------------------------------
__global__ __launch_bounds__(256) void k4_reduce(
    const unsigned short* __restrict__ pbuf, float* __restrict__ out) {
  int orig = blockIdx.x;
  int n = (orig & 7) * 128 + (orig >> 3);  // bijective (1024 % 8 == 0)
  int base = (n * 256 + threadIdx.x) * 8;
  float s[8] = {0.f, 0.f, 0.f, 0.f, 0.f, 0.f, 0.f, 0.f};
#pragma unroll
  for (int sl = 0; sl < JC; ++sl) {
    ushort8 v = *(const ushort8*)(pbuf + (long long)sl * SLAB + base);
#pragma unroll
    for (int e = 0; e < 8; ++e)
      s[e] += __uint_as_float(((unsigned)(unsigned short)v[e]) << 16);
  }
  f32x4 o0, o1;
#pragma unroll
  for (int e = 0; e < 8; ++e) {
    float xv = s[e];
    float y = xv > 0.f ? xv : expm1f(xv);
    if (e < 4) o0[e] = y; else o1[e - 4] = y;
  }
  *(f32x4*)(out + base) = o0;
  *(f32x4*)(out + base + 4) = o1;
}

extern "C" void kernel_launch(void* const* d_in, const int* in_sizes, int n_in,
                              void* d_out, int out_size, void* d_ws,
                              size_t ws_size, hipStream_t stream) {
  const float* h = (const float*)d_in[0];
  const int* adj = (const int*)d_in[1];
  const float* W = (const float*)d_in[2];
  const float* a = (const float*)d_in[3];
  float* out = (float*)d_out;

  char* ws = (char*)d_ws;
  unsigned short* WT = (unsigned short*)ws;                  // 64 KB
  unsigned short* whT = (unsigned short*)(ws + (1 << 20));   // 4 MB
  float* s1L = (float*)(ws + (5 << 20));                     // 64 KB
  float* s2L = s1L + 16384;                                  // 64 KB
  float2* st2 = (float2*)(ws + (5 << 20) + (128 << 10));     // 128 KB
  unsigned long long* mask64 =
      (unsigned long long*)(ws + (6 << 20));                 // 8 MB
  unsigned short* pbuf = (unsigned short*)(ws + (16 << 20)); // 32 MB bf16

  hipLaunchKernelGGL(k0_prep, dim3(8), dim3(256), 0, stream, W, WT);
  hipLaunchKernelGGL(k1b_wh, dim3(1024), dim3(256), 0, stream, h, WT, a, whT,
                     s1L, s2L);
  hipLaunchKernelGGL(k2_stats, dim3(16384), dim3(256), 0, stream, adj, s1L,
                     s2L, st2, mask64);
  hipLaunchKernelGGL(k3_pv, dim3(1024), dim3(512), 0, stream, whT, st2,
                     mask64, s2L, pbuf);
  hipLaunchKernelGGL(k4_reduce, dim3(1024), dim3(256), 0, stream, pbuf, out);
}

// Round 14
// 109.221 us; speedup vs baseline: 9.6492x; 1.0022x over previous
//
#include <hip/hip_runtime.h>
#include <hip/hip_bf16.h>

#define ALPHA 0.2f
#define L2E 1.4426950408889634f

constexpr int Nn = 4096;
constexpr int FIN = 256;
constexpr int FOUT = 128;
constexpr int JC = 8;    // j-split for k3
constexpr int JQ = 512;  // j per k3 block
constexpr int NCH = 8;   // 64-j chunks per k3 block (was 16x32: half barriers)
constexpr long long SLAB = 2097152;  // 4*4096*128 elems per partial slab

typedef __attribute__((ext_vector_type(8))) short short8;
typedef __attribute__((ext_vector_type(8))) unsigned short ushort8;
typedef __attribute__((ext_vector_type(4))) float f32x4;
typedef __attribute__((ext_vector_type(4))) int int4v;
typedef __attribute__((ext_vector_type(4))) unsigned int uint4v;

__device__ __forceinline__ unsigned short f2bf(float x) {
  unsigned int u = __float_as_uint(x);
  unsigned int r = (u + 0x7fffu + ((u >> 16) & 1u)) >> 16;
  return (unsigned short)r;
}

__device__ __forceinline__ float bf2f(unsigned short v) {
  return __uint_as_float(((unsigned)v) << 16);
}

__device__ __forceinline__ void gload16(const void* g, void* l) {
  auto lp = (__attribute__((address_space(3))) void*)l;
  auto gp = (const __attribute__((address_space(1))) void*)g;
  __builtin_amdgcn_global_load_lds(gp, lp, 16, 0, 0);
}

// ---------------------------------------------------------------------------
// k0: WT bf16 [i=128][k=256] from W f32 [k][i] (LDS transpose). Grid 8.
// ---------------------------------------------------------------------------
__global__ __launch_bounds__(256) void k0_prep(
    const float* __restrict__ W, unsigned short* __restrict__ WT) {
  __shared__ float lw[32][132];
  int t = threadIdx.x;
  int kc0 = blockIdx.x * 32;
#pragma unroll
  for (int m = 0; m < 4; ++m) {
    int idx = t * 16 + m * 4;
    f32x4 v = *(const f32x4*)(W + kc0 * 128 + idx);
    int k = idx >> 7, i0 = idx & 127;
    *(f32x4*)&lw[k][i0] = v;
  }
  __syncthreads();
  int i = t >> 1, half = t & 1;
  unsigned short pk[16];
#pragma unroll
  for (int kk = 0; kk < 16; ++kk) pk[kk] = f2bf(lw[half * 16 + kk][i]);
  ushort8* dst = (ushort8*)(WT + i * 256 + kc0 + half * 16);
  dst[0] = *(ushort8*)&pk[0];
  dst[1] = *(ushort8*)&pk[8];
}

// ---------------------------------------------------------------------------
// k1b: Wh via mfma_16x16x32_bf16. 16-row blocks, grid 1024.
// Emits whT bf16 [b][i=128][n=4096] AND s1L/s2L (x log2 e).
// ---------------------------------------------------------------------------
__global__ __launch_bounds__(256) void k1b_wh(
    const float* __restrict__ h, const unsigned short* __restrict__ WT,
    const float* __restrict__ a, unsigned short* __restrict__ whT,
    float* __restrict__ s1L, float* __restrict__ s2L) {
  __shared__ __align__(16) char smem[36864];
  int t = threadIdx.x;
  int w = t >> 6, l = t & 63, g = l >> 4, r = l & 15;
  int r0 = blockIdx.x * 16;
  int b = r0 >> 12, nbase = r0 & 4095;

  f32x4 acc[2];
  acc[0] = (f32x4){0.f, 0.f, 0.f, 0.f};
  acc[1] = (f32x4){0.f, 0.f, 0.f, 0.f};

  for (int kc = 0; kc < 2; ++kc) {
    __syncthreads();
    {
      int row = t >> 4, sec = t & 15;
      const f32x4* src =
          (const f32x4*)(h + (long long)(r0 + row) * 256 + kc * 128 + sec * 8);
      f32x4 v0 = src[0], v1 = src[1];
      unsigned int pk[4];
      pk[0] = ((unsigned)f2bf(v0.y) << 16) | f2bf(v0.x);
      pk[1] = ((unsigned)f2bf(v0.w) << 16) | f2bf(v0.z);
      pk[2] = ((unsigned)f2bf(v1.y) << 16) | f2bf(v1.x);
      pk[3] = ((unsigned)f2bf(v1.w) << 16) | f2bf(v1.z);
      *(ushort8*)(smem + row * 256 + ((sec ^ (row & 7)) << 4)) = *(ushort8*)pk;
    }
    {
      int i = t >> 1, pt = t & 1;
      const ushort8* src = (const ushort8*)(WT + i * 256 + kc * 128 + pt * 64);
#pragma unroll
      for (int m = 0; m < 8; ++m) {
        ushort8 v = src[m];
        int slot = pt * 8 + m;
        *(ushort8*)(smem + 4096 + i * 256 + ((slot ^ (i & 7)) << 4)) = v;
      }
    }
    __syncthreads();
#pragma unroll
    for (int kk = 0; kk < 4; ++kk) {
      short8 af =
          *(const short8*)(smem + r * 256 + (((kk * 4 + g) ^ (r & 7)) << 4));
#pragma unroll
      for (int s = 0; s < 2; ++s) {
        int i = w * 32 + s * 16 + r;
        short8 bf = *(const short8*)(smem + 4096 + i * 256 +
                                     (((kk * 4 + g) ^ (i & 7)) << 4));
        acc[s] =
            __builtin_amdgcn_mfma_f32_16x16x32_bf16(af, bf, acc[s], 0, 0, 0);
      }
    }
  }

  __syncthreads();
  unsigned short* tb = (unsigned short*)smem;  // [128][25]
#pragma unroll
  for (int s = 0; s < 2; ++s)
#pragma unroll
    for (int q = 0; q < 4; ++q)
      tb[(w * 32 + s * 16 + r) * 25 + g * 4 + q] = f2bf(acc[s][q]);
  __syncthreads();

  {
    int i = t >> 1, half = t & 1;
    ushort8 v = *(const ushort8*)(tb + i * 25 + half * 8);
    *(ushort8*)(whT + (((long long)(b * 128 + i)) << 12) + nbase + half * 8) =
        v;
  }
  {
    int n = t >> 4, seg = t & 15;
    f32x4 a10 = *(const f32x4*)(a + seg * 8);
    f32x4 a11 = *(const f32x4*)(a + seg * 8 + 4);
    f32x4 a20 = *(const f32x4*)(a + 128 + seg * 8);
    f32x4 a21 = *(const f32x4*)(a + 128 + seg * 8 + 4);
    float v1 = 0.f, v2 = 0.f;
#pragma unroll
    for (int m = 0; m < 8; ++m) {
      float wh = bf2f(tb[(seg * 8 + m) * 25 + n]);
      float c1 = (m < 4) ? a10[m] : a11[m - 4];
      float c2 = (m < 4) ? a20[m] : a21[m - 4];
      v1 += wh * c1;
      v2 += wh * c2;
    }
#pragma unroll
    for (int off = 8; off; off >>= 1) {
      v1 += __shfl_xor(v1, off);
      v2 += __shfl_xor(v2, off);
    }
    if (seg == 0) {
      s1L[r0 + n] = v1 * L2E;
      s2L[r0 + n] = v2 * L2E;
    }
  }
}

// ---------------------------------------------------------------------------
// k2: block-per-row, coalesced NT int4 adj loads, single-pass no-max softmax
// in exp2 domain; mask via shfl_xor nibble merge. st2[row] = {E1, E2} where
// E1 = exp2(s1L+negc), E2 = exp2(ALPHA*s1L+negc) -- factorized for k3.
// ---------------------------------------------------------------------------
__global__ __launch_bounds__(256) void k2_stats(
    const int* __restrict__ adj, const float* __restrict__ s1L,
    const float* __restrict__ s2L, float2* __restrict__ st2,
    unsigned long long* __restrict__ mask64) {
  __shared__ unsigned int mwords[128];
  __shared__ float wsum[4];
  int row = blockIdx.x;
  int b = row >> 12;
  int t = threadIdx.x;
  float s1j = s1L[row];
  const int4v* arow = (const int4v*)(adj + (long long)row * Nn);
  const f32x4* s2v = (const f32x4*)(s2L + (b << 12));

  float sum = 0.f;
#pragma unroll
  for (int q = 0; q < 4; ++q) {
    int4v av = __builtin_nontemporal_load(arow + q * 256 + t);
    f32x4 sv = s2v[q * 256 + t];
    unsigned nib = 0;
#pragma unroll
    for (int c = 0; c < 4; ++c) {
      float u = s1j + sv[c];
      float vL = fmaxf(u, ALPHA * u);
      float e = exp2f(vL);
      sum = fmaf((float)av[c], e, sum);  // adj in {0,1}
      nib |= ((unsigned)av[c]) << c;
    }
    unsigned n1 = nib | (__shfl_xor(nib, 1) << 4);
    unsigned n2 = n1 | (__shfl_xor(n1, 2) << 8);
    unsigned n4 = n2 | (__shfl_xor(n2, 4) << 16);
    if ((t & 7) == 0) mwords[q * 32 + (t >> 3)] = n4;
  }
#pragma unroll
  for (int off = 32; off; off >>= 1) sum += __shfl_xor(sum, off);
  if ((t & 63) == 0) wsum[t >> 6] = sum;
  __syncthreads();
  if (t < 64) {
    unsigned long long mv = *(unsigned long long*)&mwords[t * 2];
    mask64[((long long)row << 6) + t] = mv;
  }
  if (t == 0) {
    float S = wsum[0] + wsum[1] + wsum[2] + wsum[3];
    float negc = (S > 0.f) ? -log2f(S) : -1.0e30f;
    st2[row] =
        make_float2(exp2f(s1j + negc), exp2f(ALPHA * s1j + negc));
  }
}

// ---------------------------------------------------------------------------
// k3: bf16 partial[jc][b][k][i] = sum_{j in eighth} p[j,k]*Wh[j,i].
// Factorized A-build (p = max(E1*F1, E2*F2), masked). 16x16x32 MFMA.
// 64-j chunks (NCH=8): 2 MFMA K-steps per barrier -- halves the
// vmcnt(0)+barrier drains and doubles the prefetch-hiding window.
// Grid 1024 = 4b x 8jc x 32kt. LDS 44KB: whT dbuf 2x16K @0 (granule
// g = gj*128+gi, gj=j-oct 0..7), mask planes mk[4][512] @32K, stl @40K.
// 3 blocks/CU = 24 waves/CU = 6/SIMD (VGPR-capped, unchanged).
// ---------------------------------------------------------------------------
__global__ __launch_bounds__(512, 6) void k3_pv(
    const unsigned short* __restrict__ whT, const float2* __restrict__ st2,
    const unsigned long long* __restrict__ mask64,
    const float* __restrict__ s2L, unsigned short* __restrict__ pbuf) {
  __shared__ __align__(16) char smem[45056];
  unsigned int* mkpl = (unsigned int*)(smem + 32768);  // [4][512]
  float2* stl = (float2*)(smem + 40960);               // [512]

  int t = threadIdx.x;
  int orig = blockIdx.x;
  int x = orig & 7, mm = orig >> 3;
  int b = x >> 1;
  int kt = ((x & 1) << 4) | (mm & 15);  // 0..31
  int jc = mm >> 4;                     // 0..7
  int w = t >> 6, l = t & 63;
  int lh = l >> 4;   // 0..3: j-subgroup (A/B K-group)
  int lo = l & 15;   // 0..15: A-row (k) / B-col (i)
  int ks = w;        // 8 k-subs x 16
  int jq0 = jc * JQ;
  long long brow = (long long)(b << 12);
  int k0g = kt << 7;  // KT = 128
  float z1 = s2L[brow + k0g + ks * 16 + lo];
  float F1 = exp2f(z1);
  float F2 = exp2f(ALPHA * z1);
  int sh31 = 31 - (((ks & 1) << 4) + lo);
  int wsel = ks >> 1;  // u32 mask plane

  // stage-once: stl (4KB via gload16), mask planes (reg-staged scatter)
  if (t < 256) gload16(st2 + brow + jq0 + t * 2, (char*)stl + t * 16);
  {
    uint4v mrow = *(const uint4v*)((const char*)(mask64 +
                                                 ((brow + jq0 + t) << 6)) +
                                   kt * 16);
    mkpl[0 * 512 + t] = mrow[0];
    mkpl[1 * 512 + t] = mrow[1];
    mkpl[2 * 512 + t] = mrow[2];
    mkpl[3 * 512 + t] = mrow[3];
  }
  // whT staging: thread t -> granules t (gj=t>>7, 0..3) and t+512 (gj+4).
  // For fixed gi the 8 gj-octs are 128B contiguous in whT (2 cache lines).
  const unsigned short* whTb = whT + ((long long)b << 19);
  int gi = t & 127;
  const unsigned short* wsrcL =
      whTb + (long long)gi * 4096 + jq0 + (t >> 7) * 8;
  const unsigned short* wsrcH = wsrcL + 32;  // gj + 4
  gload16(wsrcL, smem + t * 16);
  gload16(wsrcH, smem + (t + 512) * 16);
  __syncthreads();

  f32x4 acc[8];
#pragma unroll
  for (int q = 0; q < 8; ++q) acc[q] = (f32x4){0.f, 0.f, 0.f, 0.f};

  const unsigned int* mkw = mkpl + wsel * 512;
  for (int ch = 0; ch < NCH; ++ch) {
    int cur = ch & 1;
    if (ch + 1 < NCH) {
      char* nb = smem + (cur ^ 1) * 16384;
      gload16(wsrcL + (ch + 1) * 64, nb + t * 16);
      gload16(wsrcH + (ch + 1) * 64, nb + (t + 512) * 16);
    }
    char* wb = smem + cur * 16384;
#pragma unroll
    for (int s = 0; s < 2; ++s) {
      int jb = ch * 64 + s * 32 + lh * 8;  // this lane-group's 8 j's
      uint4v mw0 = *(const uint4v*)(mkw + jb);
      uint4v mw1 = *(const uint4v*)(mkw + jb + 4);
      const f32x4* stp = (const f32x4*)(stl + jb);  // 16B-aligned (jb even)
      f32x4 sA = stp[0], sB = stp[1], sC = stp[2], sD = stp[3];
      short8 af;
#pragma unroll
      for (int e = 0; e < 8; ++e) {
        f32x4 sv = (e < 2) ? sA : (e < 4) ? sB : (e < 6) ? sC : sD;
        float E1 = (e & 1) ? sv.z : sv.x;
        float E2 = (e & 1) ? sv.w : sv.y;
        unsigned mv = (e < 4) ? mw0[e] : mw1[e - 4];
        float p = fmaxf(E1 * F1, E2 * F2);
        int msk = ((int)(mv << sh31)) >> 31;
        unsigned pu = __float_as_uint(p) & (unsigned)msk;
        __hip_bfloat16 hb = __float2bfloat16(__uint_as_float(pu));
        af[e] = *(short*)&hb;
      }
      int gb = (s * 4 + lh) * 128;
#pragma unroll
      for (int q = 0; q < 8; ++q) {
        short8 bv = *(const short8*)(wb + ((gb + q * 16 + lo) << 4));
        acc[q] =
            __builtin_amdgcn_mfma_f32_16x16x32_bf16(af, bv, acc[q], 0, 0, 0);
      }
    }
    __syncthreads();
  }

  // store: D col = lo (i within tile), row = lh*4 + r (k within 16)
  unsigned short* pb = pbuf + (long long)jc * SLAB + ((brow + k0g) << 7);
#pragma unroll
  for (int q = 0; q < 8; ++q) {
#pragma unroll
    for (int r = 0; r < 4; ++r) {
      int kl = ks * 16 + lh * 4 + r;
      pb[kl * 128 + q * 16 + lo] = f2bf(acc[q][r]);
    }
  }
}

// ---------------------------------------------------------------------------
// k4: out = elu(sum_jc bf16 partial). Grid 1024 x 256, 8 elems/thread.
// Swizzle reads tile n from the XCD (n>>7) where k3 wrote it.
// ---------------------------------------------------------------------------
__global__ __launch_bounds__(256) void k4_reduce(
    const unsigned short* __restrict__ pbuf, float* __restrict__ out) {
  int orig = blockIdx.x;
  int n = (orig & 7) * 128 + (orig >> 3);  // bijective (1024 % 8 == 0)
  int base = (n * 256 + threadIdx.x) * 8;
  float s[8] = {0.f, 0.f, 0.f, 0.f, 0.f, 0.f, 0.f, 0.f};
#pragma unroll
  for (int sl = 0; sl < JC; ++sl) {
    ushort8 v = *(const ushort8*)(pbuf + (long long)sl * SLAB + base);
#pragma unroll
    for (int e = 0; e < 8; ++e)
      s[e] += __uint_as_float(((unsigned)(unsigned short)v[e]) << 16);
  }
  f32x4 o0, o1;
#pragma unroll
  for (int e = 0; e < 8; ++e) {
    float xv = s[e];
    float y = xv > 0.f ? xv : expm1f(xv);
    if (e < 4) o0[e] = y; else o1[e - 4] = y;
  }
  *(f32x4*)(out + base) = o0;
  *(f32x4*)(out + base + 4) = o1;
}

extern "C" void kernel_launch(void* const* d_in, const int* in_sizes, int n_in,
                              void* d_out, int out_size, void* d_ws,
                              size_t ws_size, hipStream_t stream) {
  const float* h = (const float*)d_in[0];
  const int* adj = (const int*)d_in[1];
  const float* W = (const float*)d_in[2];
  const float* a = (const float*)d_in[3];
  float* out = (float*)d_out;

  char* ws = (char*)d_ws;
  unsigned short* WT = (unsigned short*)ws;                  // 64 KB
  unsigned short* whT = (unsigned short*)(ws + (1 << 20));   // 4 MB
  float* s1L = (float*)(ws + (5 << 20));                     // 64 KB
  float* s2L = s1L + 16384;                                  // 64 KB
  float2* st2 = (float2*)(ws + (5 << 20) + (128 << 10));     // 128 KB
  unsigned long long* mask64 =
      (unsigned long long*)(ws + (6 << 20));                 // 8 MB
  unsigned short* pbuf = (unsigned short*)(ws + (16 << 20)); // 32 MB bf16

  hipLaunchKernelGGL(k0_prep, dim3(8), dim3(256), 0, stream, W, WT);
  hipLaunchKernelGGL(k1b_wh, dim3(1024), dim3(256), 0, stream, h, WT, a, whT,
                     s1L, s2L);
  hipLaunchKernelGGL(k2_stats, dim3(16384), dim3(256), 0, stream, adj, s1L,
                     s2L, st2, mask64);
  hipLaunchKernelGGL(k3_pv, dim3(1024), dim3(512), 0, stream, whT, st2,
                     mask64, s2L, pbuf);
  hipLaunchKernelGGL(k4_reduce, dim3(1024), dim3(256), 0, stream, pbuf, out);
}